// Round 4
// baseline (997.011 us; speedup 1.0000x reference)
//
#include <hip/hip_runtime.h>

typedef __attribute__((ext_vector_type(8))) short bf16x8;
typedef __attribute__((ext_vector_type(4))) short s16x4;
typedef __attribute__((ext_vector_type(4))) float f32x4;
typedef unsigned short ushort_t;

#define LOG2E 1.44269504088896340736f
#define EXP_BIAS 23.08312066f          /* 16 * LOG2E */
#define Q_SCALE 0.18033688f            /* 0.125 * LOG2E */

// ---------- helpers ----------
__device__ __forceinline__ unsigned short f2bf(float x) {
  unsigned int u = __float_as_uint(x);
  u = (u + 0x7FFFu + ((u >> 16) & 1u)) >> 16;   // RNE
  return (unsigned short)u;
}

__device__ __forceinline__ void async16(void* lds_dst, const void* gsrc) {
  __builtin_amdgcn_global_load_lds(
      (const __attribute__((address_space(1))) void*)gsrc,
      (__attribute__((address_space(3))) void*)lds_dst, 16, 0, 0);
}

// ---------- fp32 -> bf16 row-major (vectorized) ----------
__global__ __launch_bounds__(256) void f32_to_bf16_vec(
    const float* __restrict__ in, ushort_t* __restrict__ out, int n8) {
  int i = blockIdx.x * 256 + threadIdx.x;
  if (i >= n8) return;
  const float4* p = (const float4*)in + (size_t)i * 2;
  float4 a = p[0], b = p[1];
  bf16x8 v;
  v[0] = (short)f2bf(a.x); v[1] = (short)f2bf(a.y);
  v[2] = (short)f2bf(a.z); v[3] = (short)f2bf(a.w);
  v[4] = (short)f2bf(b.x); v[5] = (short)f2bf(b.y);
  v[6] = (short)f2bf(b.z); v[7] = (short)f2bf(b.w);
  *((bf16x8*)out + i) = v;
}

// ---------- transpose fp32 (Kd x N) -> bf16 (Npad x Kd), zero-pad rows >= N ----------
__global__ __launch_bounds__(256) void transpose_w_bf16(
    const float* __restrict__ in, ushort_t* __restrict__ out, int N, int Kd) {
  __shared__ float tile[32][33];
  const int tx = threadIdx.x & 31, ty = threadIdx.x >> 5;
  const int n0 = blockIdx.x * 32, k0 = blockIdx.y * 32;
#pragma unroll
  for (int yy = 0; yy < 32; yy += 8) {
    int k = k0 + ty + yy;
    int n = n0 + tx;
    tile[ty + yy][tx] = (n < N) ? in[(size_t)k * N + n] : 0.f;
  }
  __syncthreads();
#pragma unroll
  for (int yy = 0; yy < 32; yy += 8) {
    int n = n0 + ty + yy;
    int k = k0 + tx;
    out[(size_t)n * Kd + k] = f2bf(tile[tx][ty + yy]);
  }
}

// ---------- 128x128-tile bf16 GEMM, BK=64, C = A(MxK) @ Bt(NpadxK)^T, fp32 out ----------
// BK=64: stage two 32-K chunks per barrier pair -> barrier count halves (the
// vmcnt(0)-before-barrier drain is the m97 structure's ~20% stall). LDS 32KB
// (occupancy stays VGPR-capped at 3 blocks/CU).
// split==1: blockIdx.x&1 selects K-half (2304/2240, both %64==0) and output
// buffer (C0 or C1); halves summed by the CONSUMER (no atomics, no zeroing).
__global__ __launch_bounds__(256) void gemm_bt_128(
    const ushort_t* __restrict__ A, const ushort_t* __restrict__ Bt,
    float* __restrict__ C0, float* __restrict__ C1,
    int N, int K, int ldc, int split) {
  __shared__ __align__(16) char lds[32768];  // half0: A[0,8K) B[8K,16K); half1: +16K
  const int tid = threadIdx.x;
  const int lane = tid & 63, wave = tid >> 6;
  const int quad = lane >> 4, col = lane & 15;
  const int bm = split ? ((int)blockIdx.x >> 1) : (int)blockIdx.x;
  const int half = split ? ((int)blockIdx.x & 1) : 0;
  const int bn = blockIdx.y;
  float* __restrict__ C = half ? C1 : C0;
  int ks, ke;
  if (split) {
    const int s0 = ((((K >> 6) + 1) >> 1) << 6);         // 2304 for K=4544
    ks = half ? s0 : 0;
    ke = half ? K : s0;
  } else { ks = 0; ke = K; }
  const int wr = (wave >> 1) * 64, wc = (wave & 1) * 64;

  const int c0 = tid, c1 = tid + 256;
  const int r0 = c0 >> 2, r1 = c1 >> 2;
  const int l0 = (c0 & 3) ^ ((r0 >> 1) & 3);
  const int l1 = (c1 & 3) ^ ((r1 >> 1) & 3);
  const ushort_t* a0 = A + (size_t)(bm * 128 + r0) * K + l0 * 8;
  const ushort_t* a1 = A + (size_t)(bm * 128 + r1) * K + l1 * 8;
  const ushort_t* b0 = Bt + (size_t)(bn * 128 + r0) * K + l0 * 8;
  const ushort_t* b1 = Bt + (size_t)(bn * 128 + r1) * K + l1 * 8;
  const int wb = wave * 1024;

  f32x4 acc[4][4];
#pragma unroll
  for (int i = 0; i < 4; ++i)
#pragma unroll
    for (int j = 0; j < 4; ++j) acc[i][j] = (f32x4){0.f, 0.f, 0.f, 0.f};

  const int ccsw = (col >> 1) & 3;
  int aoff[4], boff[4];
#pragma unroll
  for (int t = 0; t < 4; ++t) {
    aoff[t] = (wr + t * 16 + col) * 64 + ((quad ^ ccsw) << 4);
    boff[t] = 8192 + (wc + t * 16 + col) * 64 + ((quad ^ ccsw) << 4);
  }

#pragma unroll 1
  for (int k = ks; k < ke; k += 64) {
    __syncthreads();
    async16(lds + wb,                   a0 + k);
    async16(lds + wb + 4096,            a1 + k);
    async16(lds + 8192 + wb,            b0 + k);
    async16(lds + 8192 + wb + 4096,     b1 + k);
    async16(lds + 16384 + wb,           a0 + k + 32);
    async16(lds + 16384 + wb + 4096,    a1 + k + 32);
    async16(lds + 24576 + wb,           b0 + k + 32);
    async16(lds + 24576 + wb + 4096,    b1 + k + 32);
    __syncthreads();
#pragma unroll
    for (int kk = 0; kk < 2; ++kk) {
      const char* base = lds + kk * 16384;
      bf16x8 af[4], bfr[4];
#pragma unroll
      for (int t = 0; t < 4; ++t) {
        af[t]  = *(const bf16x8*)(base + aoff[t]);
        bfr[t] = *(const bf16x8*)(base + boff[t]);
      }
#pragma unroll
      for (int i = 0; i < 4; ++i)
#pragma unroll
        for (int j = 0; j < 4; ++j)
          acc[i][j] = __builtin_amdgcn_mfma_f32_16x16x32_bf16(af[i], bfr[j], acc[i][j], 0, 0, 0);
    }
  }

#pragma unroll
  for (int i = 0; i < 4; ++i) {
    const int row = bm * 128 + wr + i * 16 + quad * 4;
#pragma unroll
    for (int j = 0; j < 4; ++j) {
      const int cc = bn * 128 + wc + j * 16 + col;
      if (cc < N) {
#pragma unroll
        for (int r = 0; r < 4; ++r)
          C[(size_t)(row + r) * ldc + cc] = acc[i][j][r];
      }
    }
  }
}

// ---------- out[i] += src[i], float4 ----------
__global__ __launch_bounds__(256) void add_inplace_f4(
    float* __restrict__ dst, const float* __restrict__ src, int n4) {
  int i = blockIdx.x * 256 + threadIdx.x;
  if (i >= n4) return;
  float4 a = ((const float4*)dst)[i];
  float4 b = ((const float4*)src)[i];
  a.x += b.x; a.y += b.y; a.z += b.z; a.w += b.w;
  ((float4*)dst)[i] = a;
}

// ---------- RoPE + split fused(2048x4672) -> Qr(/8*log2e, bf16), Kr, Vt; zero ssum ----------
// two==1: fused = f0 + f1 (split-K GEMM halves summed here, fused into the pass)
__global__ __launch_bounds__(256) void rope_split(
    const float* __restrict__ f0, const float* __restrict__ f1, int two,
    ushort_t* __restrict__ Qr, ushort_t* __restrict__ Kr,
    ushort_t* __restrict__ Vt, float* __restrict__ ssum) {
  const int spos = blockIdx.x;
  const float* row0 = f0 + (size_t)spos * 4672;
  const float* row1 = f1 + (size_t)spos * 4672;
  if (blockIdx.x == 0)
    for (int j = threadIdx.x; j < 2048; j += 256) ssum[j] = 0.f;
  for (int c = threadIdx.x; c < 4672; c += 256) {
    const int hh = c >> 6, d = c & 63, j = d & 31;
    const float x = two ? (row0[c] + row1[c]) : row0[c];
    if (hh == 72) { Vt[(size_t)d * 2048 + spos] = f2bf(x); continue; }
    // 10000^(-j/32) = exp2(-j * log2(10000)/32)
    const float freq = __builtin_amdgcn_exp2f((float)j * -0.41524101186f);
    const float ang = (float)spos * freq;
    float sv, cv;
    __sincosf(ang, &sv, &cv);
    const int cp = (d < 32) ? c + 32 : c - 32;
    const float partner = two ? (row0[cp] + row1[cp]) : row0[cp];
    const float val = (d < 32) ? (x * cv - partner * sv) : (x * cv + partner * sv);
    if (hh == 71) Kr[(size_t)spos * 64 + d] = f2bf(val);
    else          Qr[(size_t)spos * 4544 + c] = f2bf(val * Q_SCALE);  // fold 1/sqrt(64)*log2e
  }
}

// ---------- flash MQA attention, fixed-base softmax (C=16), S^T orientation ----------
// block = 256 queries x 1 head (2 q-groups of 128); 4 waves; wave owns q-rows
// {qw, qw+128}. One staged K/V tile feeds BOTH groups sequentially (pbuf is
// per-wave scratch, reused g=0 then g=1 -> no extra LDS, no extra barrier).
// Barrier-tiles per head: 272 -> 144; staging bytes halve; compute unchanged.
// Inner math identical to the verified round-0/3 code with qw -> qw + g*128.
__global__ __launch_bounds__(256) void attn_flash(
    const ushort_t* __restrict__ Qr, const ushort_t* __restrict__ Kr,
    const ushort_t* __restrict__ Vt, ushort_t* __restrict__ merged,
    float* __restrict__ ssum) {
  const int qb2 = (int)gridDim.x - 1 - (int)blockIdx.x;  // heavy blocks first
  const int h = blockIdx.y;
  const int q0 = qb2 * 256;
  const int tid = threadIdx.x, wave = tid >> 6, lane = tid & 63;
  const int quad = lane >> 4, col = lane & 15;
  const int qw = q0 + wave * 32;                         // group-0 rows; group-1 = +128
  const int ntiles = (qb2 + 1) * 4;                      // 64-key tiles

  __shared__ __align__(16) ushort_t kbuf[64 * 72];
  __shared__ __align__(16) ushort_t vbuf[64 * 72];
  __shared__ __align__(16) char pcs[4 * 32 * 72 * 2];    // pbuf (s1) / cs (s2)
  ushort_t* pbuf = (ushort_t*)pcs + wave * (32 * 72);    // P^T: [32 q][64 k] stride 72
  float* cs = (float*)pcs;

  const int c0 = tid * 2;
  const int srow = c0 >> 3, sg = c0 & 7;

  // Q fragments: rows qw+g*128+nt*16+col (serve as B in sweep1, A in sweep2)
  bf16x8 qf[2][2][2];
#pragma unroll
  for (int g = 0; g < 2; ++g)
#pragma unroll
    for (int nt = 0; nt < 2; ++nt)
#pragma unroll
      for (int s = 0; s < 2; ++s)
        qf[g][nt][s] = *(const bf16x8*)(Qr + (size_t)(qw + g * 128 + nt * 16 + col) * 4544 + h * 64 + s * 32 + quad * 8);

  f32x4 oacc[2][2][4];                                   // [g][ntile q][mtile d] of O^T
  float l[2][2] = {{0.f, 0.f}, {0.f, 0.f}};
#pragma unroll
  for (int g = 0; g < 2; ++g)
#pragma unroll
    for (int nt = 0; nt < 2; ++nt)
#pragma unroll
      for (int m = 0; m < 4; ++m) oacc[g][nt][m] = (f32x4){0.f, 0.f, 0.f, 0.f};

  // ---- sweep 1 ----
  for (int t = 0; t < ntiles; ++t) {
    const int kbase = t * 64;
    __syncthreads();
    {
      const ushort_t* ks = Kr + (size_t)(kbase + srow) * 64 + sg * 8;
      ushort_t* kd = kbuf + srow * 72 + sg * 8;
      *(bf16x8*)kd = *(const bf16x8*)ks;
      *(bf16x8*)(kd + 8) = *(const bf16x8*)(ks + 8);
      const ushort_t* vs = Vt + (size_t)srow * 2048 + kbase + sg * 8;
      ushort_t* vd = vbuf + srow * 72 + sg * 8;
      *(bf16x8*)vd = *(const bf16x8*)vs;
      *(bf16x8*)(vd + 8) = *(const bf16x8*)(vs + 8);
    }
    __syncthreads();
    if (kbase > qw + 128 + 31) continue;                 // both groups masked

    bf16x8 kf[4][2];                                     // A-frags: rows = keys
#pragma unroll
    for (int m = 0; m < 4; ++m) {
      kf[m][0] = *(const bf16x8*)(kbuf + (m * 16 + col) * 72 + quad * 8);
      kf[m][1] = *(const bf16x8*)(kbuf + (m * 16 + col) * 72 + 32 + quad * 8);
    }
#pragma unroll
    for (int g = 0; g < 2; ++g) {
      const int qg = qw + g * 128;
      if (kbase > qg + 31) continue;                     // this group masked
      // S^T per ntile; pack P^T rows (4 consecutive keys per lane) as b64
#pragma unroll
      for (int nt = 0; nt < 2; ++nt) {
        const int qmin = qg + nt * 16;
        const int qtop = qmin + 15;
        if (kbase > qtop) continue;
        const int q = qmin + col;
#pragma unroll
        for (int m = 0; m < 4; ++m) {
          const int kb2 = kbase + m * 16;
          s16x4 pk;
          if (kb2 > qtop) {                              // fully above diagonal: p == 0
            pk[0] = 0; pk[1] = 0; pk[2] = 0; pk[3] = 0;
            *(s16x4*)(pbuf + (nt * 16 + col) * 72 + m * 16 + quad * 4) = pk;
            continue;
          }
          f32x4 sacc = (f32x4){0.f, 0.f, 0.f, 0.f};
          sacc = __builtin_amdgcn_mfma_f32_16x16x32_bf16(kf[m][0], qf[g][nt][0], sacc, 0, 0, 0);
          sacc = __builtin_amdgcn_mfma_f32_16x16x32_bf16(kf[m][1], qf[g][nt][1], sacc, 0, 0, 0);
          float ls = 0.f;
          if (kb2 + 15 <= qmin) {                        // fully below diagonal: no mask
#pragma unroll
            for (int r = 0; r < 4; ++r) {
              const float px = __builtin_amdgcn_exp2f(sacc[r] - EXP_BIAS);
              ls += px;
              pk[r] = (short)f2bf(px);
            }
          } else {                                       // diagonal block: per-element mask
#pragma unroll
            for (int r = 0; r < 4; ++r) {
              const int key = kb2 + quad * 4 + r;
              const float px = __builtin_amdgcn_exp2f(sacc[r] - EXP_BIAS);
              const float p = (key <= q) ? px : 0.f;
              ls += p;
              pk[r] = (short)f2bf(p);
            }
          }
          l[g][nt] += ls;
          *(s16x4*)(pbuf + (nt * 16 + col) * 72 + m * 16 + quad * 4) = pk;
        }
      }
      // PV: O^T += V^T · P^T  (A = vbuf d-rows, B = pbuf q-rows)
#pragma unroll
      for (int ch = 0; ch < 2; ++ch) {
        if (kbase + ch * 32 > qg + 31) continue;
        bf16x8 vf[4];
#pragma unroll
        for (int m = 0; m < 4; ++m)
          vf[m] = *(const bf16x8*)(vbuf + (m * 16 + col) * 72 + ch * 32 + quad * 8);
#pragma unroll
        for (int nt = 0; nt < 2; ++nt) {
          if (kbase + ch * 32 > qg + nt * 16 + 15) continue;
          const bf16x8 pf = *(const bf16x8*)(pbuf + (nt * 16 + col) * 72 + ch * 32 + quad * 8);
#pragma unroll
          for (int m = 0; m < 4; ++m)
            oacc[g][nt][m] = __builtin_amdgcn_mfma_f32_16x16x32_bf16(vf[m], pf, oacc[g][nt][m], 0, 0, 0);
        }
      }
    }
  }

  // l: per-lane partials cover keys == quad*4+r (mod 16); reduce across quads
  float invl[2][2];
#pragma unroll
  for (int g = 0; g < 2; ++g)
#pragma unroll
    for (int nt = 0; nt < 2; ++nt) {
      float v = l[g][nt];
      v += __shfl_xor(v, 16, 64);
      v += __shfl_xor(v, 32, 64);
      invl[g][nt] = 1.0f / v;
    }

  // write O^T: lane holds 4 consecutive d for query qg+nt*16+col -> b64 stores
#pragma unroll
  for (int g = 0; g < 2; ++g)
#pragma unroll
    for (int nt = 0; nt < 2; ++nt)
#pragma unroll
      for (int m = 0; m < 4; ++m) {
        s16x4 ok;
#pragma unroll
        for (int r = 0; r < 4; ++r) ok[r] = (short)f2bf(oacc[g][nt][m][r] * invl[g][nt]);
        *(s16x4*)(merged + (size_t)(qw + g * 128 + nt * 16 + col) * 4544 + h * 64 + m * 16 + quad * 4) = ok;
      }

  // invl in sweep-2 row layout: query = qg + i*16 + quad*4 + r
  float linv2[2][2][4];
#pragma unroll
  for (int g = 0; g < 2; ++g)
#pragma unroll
    for (int i = 0; i < 2; ++i)
#pragma unroll
      for (int r = 0; r < 4; ++r) linv2[g][i][r] = __shfl(invl[g][i], quad * 4 + r, 16);

  // ---- sweep 2: normalized colsums, keys < 1920 only ----
  __syncthreads();                                   // pbuf reads done -> reuse as cs
  const int nk2 = min(ntiles * 64, 1920);
  const int nt2 = min(ntiles, 30);
  for (int j = tid; j < nk2; j += 256) cs[j] = 0.f;

  for (int t = 0; t < nt2; ++t) {
    const int kbase = t * 64;
    __syncthreads();
    {
      const ushort_t* ks = Kr + (size_t)(kbase + srow) * 64 + sg * 8;
      ushort_t* kd = kbuf + srow * 72 + sg * 8;
      *(bf16x8*)kd = *(const bf16x8*)ks;
      *(bf16x8*)(kd + 8) = *(const bf16x8*)(ks + 8);
    }
    __syncthreads();
    if (kbase > qw + 128 + 31) continue;

    bf16x8 kf[4][2];                                 // B-frags now: rows = keys
#pragma unroll
    for (int n = 0; n < 4; ++n) {
      kf[n][0] = *(const bf16x8*)(kbuf + (n * 16 + col) * 72 + quad * 8);
      kf[n][1] = *(const bf16x8*)(kbuf + (n * 16 + col) * 72 + 32 + quad * 8);
    }
    float accn[4] = {0.f, 0.f, 0.f, 0.f};
#pragma unroll
    for (int g = 0; g < 2; ++g) {
      const int qg = qw + g * 128;
      if (kbase > qg + 31) continue;
#pragma unroll
      for (int i = 0; i < 2; ++i) {
        const int qmin = qg + i * 16;
        const int qmax = qmin + 15;
        if (kbase > qmax) continue;
#pragma unroll
        for (int n = 0; n < 4; ++n) {
          const int kb2 = kbase + n * 16;
          if (kb2 > qmax) continue;                  // block fully masked: contributes 0
          f32x4 sacc = __builtin_amdgcn_mfma_f32_16x16x32_bf16(qf[g][i][0], kf[n][0],
                         (f32x4){0.f, 0.f, 0.f, 0.f}, 0, 0, 0);
          sacc = __builtin_amdgcn_mfma_f32_16x16x32_bf16(qf[g][i][1], kf[n][1], sacc, 0, 0, 0);
          if (kb2 + 15 <= qmin) {                    // fully unmasked
#pragma unroll
            for (int r = 0; r < 4; ++r)
              accn[n] += __builtin_amdgcn_exp2f(sacc[r] - EXP_BIAS) * linv2[g][i][r];
          } else {                                   // diagonal block
#pragma unroll
            for (int r = 0; r < 4; ++r) {
              const int q = qmin + quad * 4 + r;
              const int key = kb2 + col;
              const float px = __builtin_amdgcn_exp2f(sacc[r] - EXP_BIAS) * linv2[g][i][r];
              accn[n] += (key <= q) ? px : 0.f;
            }
          }
        }
      }
    }
#pragma unroll
    for (int n = 0; n < 4; ++n) {
      float v = accn[n];
      v += __shfl_xor(v, 16, 64);
      v += __shfl_xor(v, 32, 64);
      if (quad == 0) atomicAdd(&cs[kbase + n * 16 + col], v);
    }
  }

  __syncthreads();
  for (int j = tid; j < nk2; j += 256) atomicAdd(&ssum[j], cs[j]);
}

// ---------- top-k(128) of ssum[0..1919] -> mask (2049 floats) ----------
__global__ __launch_bounds__(1024) void topk_mask(
    const float* __restrict__ ssum, float* __restrict__ maskout) {
  __shared__ float sv[1920];
  for (int i = threadIdx.x; i < 1920; i += 1024) sv[i] = ssum[i];
  __syncthreads();
  for (int i = threadIdx.x; i < 2049; i += 1024) {
    float o;
    if (i >= 1921) o = 1.f;
    else if (i == 1920) o = 0.f;
    else {
      const float v = sv[i];
      int rank = 0;
      for (int j = 0; j < 1920; ++j) {
        const float w = sv[j];
        rank += (w > v) || (w == v && j < i);
      }
      o = (rank < 128) ? 1.f : 0.f;
    }
    maskout[i] = o;
  }
}

// ---------- launch ----------
extern "C" void kernel_launch(void* const* d_in, const int* in_sizes, int n_in,
                              void* d_out, int out_size, void* d_ws, size_t ws_size,
                              hipStream_t stream) {
  (void)in_sizes; (void)n_in; (void)out_size;
  const float* hs      = (const float*)d_in[0];   // 1x2048x4544
  const float* w_qkv   = (const float*)d_in[1];   // 4544x4672
  const float* w_dense = (const float*)d_in[2];   // 4544x4544
  float* out = (float*)d_out;                     // 2048*4544 + 2049

  char* ws = (char*)d_ws;
  constexpr size_t OFF_WT    = 0;                        // 4736x4544 bf16
  constexpr size_t OFF_HSB   = 43040768;                 // 2048x4544 bf16 (reused as merged)
  constexpr size_t OFF_FUSED = OFF_HSB + 18612224;       // 2048x4672 fp32
  constexpr size_t OFF_QR    = OFF_FUSED + 38273024;     // 2048x4544 bf16
  constexpr size_t OFF_KR    = OFF_QR + 18612224;        // 2048x64 bf16
  constexpr size_t OFF_VT    = OFF_KR + 262144;          // 64x2048 bf16
  constexpr size_t OFF_SS    = OFF_VT + 262144;          // 2048 fp32
  constexpr size_t OFF_F2    = OFF_SS + 8192;            // 2048x4672 fp32 (split-K C1)
  constexpr size_t WS_NEED   = OFF_F2 + 38273024;        // ~150.1 MiB

  ushort_t* wT     = (ushort_t*)(ws + OFF_WT);
  ushort_t* hsb    = (ushort_t*)(ws + OFF_HSB);
  float*    fused  = (float*)(ws + OFF_FUSED);
  ushort_t* qr     = (ushort_t*)(ws + OFF_QR);
  ushort_t* kr     = (ushort_t*)(ws + OFF_KR);
  ushort_t* vt     = (ushort_t*)(ws + OFF_VT);
  float*    ssum   = (float*)(ws + OFF_SS);
  float*    fused1 = (float*)(ws + OFF_F2);

  const int split = (ws_size >= WS_NEED) ? 1 : 0;        // fall back if ws too small

  f32_to_bf16_vec<<<4544, 256, 0, stream>>>(hs, hsb, 2048 * 4544 / 8);
  transpose_w_bf16<<<dim3(148, 142), 256, 0, stream>>>(w_qkv, wT, 4672, 4544);
  if (split) {
    gemm_bt_128<<<dim3(32, 37), 256, 0, stream>>>(hsb, wT, fused, fused1, 4672, 4544, 4672, 1);
    rope_split<<<2048, 256, 0, stream>>>(fused, fused1, 1, qr, kr, vt, ssum);
  } else {
    gemm_bt_128<<<dim3(16, 37), 256, 0, stream>>>(hsb, wT, fused, fused, 4672, 4544, 4672, 0);
    rope_split<<<2048, 256, 0, stream>>>(fused, fused, 0, qr, kr, vt, ssum);
  }
  transpose_w_bf16<<<dim3(144, 142), 256, 0, stream>>>(w_dense, wT, 4544, 4544);
  attn_flash<<<dim3(8, 71), 256, 0, stream>>>(qr, kr, vt, hsb, ssum);
  topk_mask<<<1, 1024, 0, stream>>>(ssum, out + (size_t)2048 * 4544);
  if (split) {
    gemm_bt_128<<<dim3(32, 36), 256, 0, stream>>>(hsb, wT, out, fused1, 4544, 4544, 4544, 1);
    add_inplace_f4<<<9088, 256, 0, stream>>>(out, fused1, 2048 * 4544 / 4);
  } else {
    gemm_bt_128<<<dim3(16, 36), 256, 0, stream>>>(hsb, wT, out, out, 4544, 4544, 4544, 0);
  }
}

// Round 5
// 801.214 us; speedup vs baseline: 1.2444x; 1.2444x over previous
//
#include <hip/hip_runtime.h>

typedef __attribute__((ext_vector_type(8))) short bf16x8;
typedef __attribute__((ext_vector_type(4))) short s16x4;
typedef __attribute__((ext_vector_type(4))) float f32x4;
typedef unsigned short ushort_t;

#define LOG2E 1.44269504088896340736f
#define EXP_BIAS 23.08312066f          /* 16 * LOG2E */
#define Q_SCALE 0.18033688f            /* 0.125 * LOG2E */

// ---------- helpers ----------
__device__ __forceinline__ unsigned short f2bf(float x) {
  unsigned int u = __float_as_uint(x);
  u = (u + 0x7FFFu + ((u >> 16) & 1u)) >> 16;   // RNE
  return (unsigned short)u;
}

__device__ __forceinline__ void async16(void* lds_dst, const void* gsrc) {
  __builtin_amdgcn_global_load_lds(
      (const __attribute__((address_space(1))) void*)gsrc,
      (__attribute__((address_space(3))) void*)lds_dst, 16, 0, 0);
}

// ---------- fp32 -> bf16 row-major (vectorized) ----------
__global__ __launch_bounds__(256) void f32_to_bf16_vec(
    const float* __restrict__ in, ushort_t* __restrict__ out, int n8) {
  int i = blockIdx.x * 256 + threadIdx.x;
  if (i >= n8) return;
  const float4* p = (const float4*)in + (size_t)i * 2;
  float4 a = p[0], b = p[1];
  bf16x8 v;
  v[0] = (short)f2bf(a.x); v[1] = (short)f2bf(a.y);
  v[2] = (short)f2bf(a.z); v[3] = (short)f2bf(a.w);
  v[4] = (short)f2bf(b.x); v[5] = (short)f2bf(b.y);
  v[6] = (short)f2bf(b.z); v[7] = (short)f2bf(b.w);
  *((bf16x8*)out + i) = v;
}

// ---------- transpose fp32 (Kd x N) -> bf16 (Npad x Kd), zero-pad rows >= N ----------
__global__ __launch_bounds__(256) void transpose_w_bf16(
    const float* __restrict__ in, ushort_t* __restrict__ out, int N, int Kd) {
  __shared__ float tile[32][33];
  const int tx = threadIdx.x & 31, ty = threadIdx.x >> 5;
  const int n0 = blockIdx.x * 32, k0 = blockIdx.y * 32;
#pragma unroll
  for (int yy = 0; yy < 32; yy += 8) {
    int k = k0 + ty + yy;
    int n = n0 + tx;
    tile[ty + yy][tx] = (n < N) ? in[(size_t)k * N + n] : 0.f;
  }
  __syncthreads();
#pragma unroll
  for (int yy = 0; yy < 32; yy += 8) {
    int n = n0 + ty + yy;
    int k = k0 + tx;
    out[(size_t)n * Kd + k] = f2bf(tile[tx][ty + yy]);
  }
}

// ---------- 128x128-tile bf16 GEMM, BK=64, C = A(MxK) @ Bt(NpadxK)^T, fp32 out ----------
// split==1: blockIdx.x&1 selects K-half (2304/2240, both %64==0) and output
// buffer (C0 or C1); halves summed by the CONSUMER (no atomics, no zeroing).
__global__ __launch_bounds__(256) void gemm_bt_128(
    const ushort_t* __restrict__ A, const ushort_t* __restrict__ Bt,
    float* __restrict__ C0, float* __restrict__ C1,
    int N, int K, int ldc, int split) {
  __shared__ __align__(16) char lds[32768];  // half0: A[0,8K) B[8K,16K); half1: +16K
  const int tid = threadIdx.x;
  const int lane = tid & 63, wave = tid >> 6;
  const int quad = lane >> 4, col = lane & 15;
  const int bm = split ? ((int)blockIdx.x >> 1) : (int)blockIdx.x;
  const int half = split ? ((int)blockIdx.x & 1) : 0;
  const int bn = blockIdx.y;
  float* __restrict__ C = half ? C1 : C0;
  int ks, ke;
  if (split) {
    const int s0 = ((((K >> 6) + 1) >> 1) << 6);         // 2304 for K=4544
    ks = half ? s0 : 0;
    ke = half ? K : s0;
  } else { ks = 0; ke = K; }
  const int wr = (wave >> 1) * 64, wc = (wave & 1) * 64;

  const int c0 = tid, c1 = tid + 256;
  const int r0 = c0 >> 2, r1 = c1 >> 2;
  const int l0 = (c0 & 3) ^ ((r0 >> 1) & 3);
  const int l1 = (c1 & 3) ^ ((r1 >> 1) & 3);
  const ushort_t* a0 = A + (size_t)(bm * 128 + r0) * K + l0 * 8;
  const ushort_t* a1 = A + (size_t)(bm * 128 + r1) * K + l1 * 8;
  const ushort_t* b0 = Bt + (size_t)(bn * 128 + r0) * K + l0 * 8;
  const ushort_t* b1 = Bt + (size_t)(bn * 128 + r1) * K + l1 * 8;
  const int wb = wave * 1024;

  f32x4 acc[4][4];
#pragma unroll
  for (int i = 0; i < 4; ++i)
#pragma unroll
    for (int j = 0; j < 4; ++j) acc[i][j] = (f32x4){0.f, 0.f, 0.f, 0.f};

  const int ccsw = (col >> 1) & 3;
  int aoff[4], boff[4];
#pragma unroll
  for (int t = 0; t < 4; ++t) {
    aoff[t] = (wr + t * 16 + col) * 64 + ((quad ^ ccsw) << 4);
    boff[t] = 8192 + (wc + t * 16 + col) * 64 + ((quad ^ ccsw) << 4);
  }

#pragma unroll 1
  for (int k = ks; k < ke; k += 64) {
    __syncthreads();
    async16(lds + wb,                   a0 + k);
    async16(lds + wb + 4096,            a1 + k);
    async16(lds + 8192 + wb,            b0 + k);
    async16(lds + 8192 + wb + 4096,     b1 + k);
    async16(lds + 16384 + wb,           a0 + k + 32);
    async16(lds + 16384 + wb + 4096,    a1 + k + 32);
    async16(lds + 24576 + wb,           b0 + k + 32);
    async16(lds + 24576 + wb + 4096,    b1 + k + 32);
    __syncthreads();
#pragma unroll
    for (int kk = 0; kk < 2; ++kk) {
      const char* base = lds + kk * 16384;
      bf16x8 af[4], bfr[4];
#pragma unroll
      for (int t = 0; t < 4; ++t) {
        af[t]  = *(const bf16x8*)(base + aoff[t]);
        bfr[t] = *(const bf16x8*)(base + boff[t]);
      }
#pragma unroll
      for (int i = 0; i < 4; ++i)
#pragma unroll
        for (int j = 0; j < 4; ++j)
          acc[i][j] = __builtin_amdgcn_mfma_f32_16x16x32_bf16(af[i], bfr[j], acc[i][j], 0, 0, 0);
    }
  }

#pragma unroll
  for (int i = 0; i < 4; ++i) {
    const int row = bm * 128 + wr + i * 16 + quad * 4;
#pragma unroll
    for (int j = 0; j < 4; ++j) {
      const int cc = bn * 128 + wc + j * 16 + col;
      if (cc < N) {
#pragma unroll
        for (int r = 0; r < 4; ++r)
          C[(size_t)(row + r) * ldc + cc] = acc[i][j][r];
      }
    }
  }
}

// ---------- out[i] += src[i], float4 ----------
__global__ __launch_bounds__(256) void add_inplace_f4(
    float* __restrict__ dst, const float* __restrict__ src, int n4) {
  int i = blockIdx.x * 256 + threadIdx.x;
  if (i >= n4) return;
  float4 a = ((const float4*)dst)[i];
  float4 b = ((const float4*)src)[i];
  a.x += b.x; a.y += b.y; a.z += b.z; a.w += b.w;
  ((float4*)dst)[i] = a;
}

// ---------- RoPE + split fused(2048x4672) -> Qr(/8*log2e, bf16), Kr, Vt; zero ssum ----------
__global__ __launch_bounds__(256) void rope_split(
    const float* __restrict__ f0, const float* __restrict__ f1, int two,
    ushort_t* __restrict__ Qr, ushort_t* __restrict__ Kr,
    ushort_t* __restrict__ Vt, float* __restrict__ ssum) {
  const int spos = blockIdx.x;
  const float* row0 = f0 + (size_t)spos * 4672;
  const float* row1 = f1 + (size_t)spos * 4672;
  if (blockIdx.x == 0)
    for (int j = threadIdx.x; j < 2048; j += 256) ssum[j] = 0.f;
  for (int c = threadIdx.x; c < 4672; c += 256) {
    const int hh = c >> 6, d = c & 63, j = d & 31;
    const float x = two ? (row0[c] + row1[c]) : row0[c];
    if (hh == 72) { Vt[(size_t)d * 2048 + spos] = f2bf(x); continue; }
    const float freq = __builtin_amdgcn_exp2f((float)j * -0.41524101186f);
    const float ang = (float)spos * freq;
    float sv, cv;
    __sincosf(ang, &sv, &cv);
    const int cp = (d < 32) ? c + 32 : c - 32;
    const float partner = two ? (row0[cp] + row1[cp]) : row0[cp];
    const float val = (d < 32) ? (x * cv - partner * sv) : (x * cv + partner * sv);
    if (hh == 71) Kr[(size_t)spos * 64 + d] = f2bf(val);
    else          Qr[(size_t)spos * 4544 + c] = f2bf(val * Q_SCALE);
  }
}

// ---------- attention sweep 1, KV-SPLIT partials ----------
// Fixed-base softmax (p = exp2(s - bias), NO running max) => partial numerator
// O and denominator l over disjoint key ranges merge by pure addition.
// Block = 128 q x 1 head x key-tile range [kt0,kt1). qb>=8 split into two
// halves (<=16 tiles; low half provably fully-unmasked), qb<8 unsplit.
// Tail model (r3/r4 evidence): makespan ~ longest block; 62 tiles -> 16.
__global__ __launch_bounds__(256) void attn_sweep1(
    const ushort_t* __restrict__ Qr, const ushort_t* __restrict__ Kr,
    const ushort_t* __restrict__ Vt, float* __restrict__ Op0,
    float* __restrict__ Op1, float* __restrict__ lp0, float* __restrict__ lp1) {
  const int bx = blockIdx.x;
  const int h = blockIdx.y;
  int qb, kt0, kt1, buf1;
  if (bx < 8)       { qb = 15 - bx;       kt0 = 0;      kt1 = qb + 1;       buf1 = 0; }
  else if (bx < 16) { qb = 15 - (bx - 8); kt0 = qb + 1; kt1 = (qb + 1) * 2; buf1 = 1; }
  else              { qb = 23 - bx;       kt0 = 0;      kt1 = (qb + 1) * 2; buf1 = 0; }
  float* __restrict__ Op = buf1 ? Op1 : Op0;
  float* __restrict__ lp = buf1 ? lp1 : lp0;
  const int q0 = qb * 128;
  const int tid = threadIdx.x, wave = tid >> 6, lane = tid & 63;
  const int quad = lane >> 4, col = lane & 15;
  const int qw = q0 + wave * 32;

  __shared__ __align__(16) ushort_t kbuf[64 * 72];
  __shared__ __align__(16) ushort_t vbuf[64 * 72];
  __shared__ __align__(16) ushort_t pbuf_s[4 * 32 * 72];
  ushort_t* pbuf = pbuf_s + wave * (32 * 72);            // P^T: [32 q][64 k] stride 72

  const int c0 = tid * 2;
  const int srow = c0 >> 3, sg = c0 & 7;

  bf16x8 qf[2][2];
#pragma unroll
  for (int nt = 0; nt < 2; ++nt)
#pragma unroll
    for (int s = 0; s < 2; ++s)
      qf[nt][s] = *(const bf16x8*)(Qr + (size_t)(qw + nt * 16 + col) * 4544 + h * 64 + s * 32 + quad * 8);

  f32x4 oacc[2][4];
  float l[2] = {0.f, 0.f};
#pragma unroll
  for (int nt = 0; nt < 2; ++nt)
#pragma unroll
    for (int m = 0; m < 4; ++m) oacc[nt][m] = (f32x4){0.f, 0.f, 0.f, 0.f};

  for (int t = kt0; t < kt1; ++t) {
    const int kbase = t * 64;
    __syncthreads();
    {
      const ushort_t* ks = Kr + (size_t)(kbase + srow) * 64 + sg * 8;
      ushort_t* kd = kbuf + srow * 72 + sg * 8;
      *(bf16x8*)kd = *(const bf16x8*)ks;
      *(bf16x8*)(kd + 8) = *(const bf16x8*)(ks + 8);
      const ushort_t* vs = Vt + (size_t)srow * 2048 + kbase + sg * 8;
      ushort_t* vd = vbuf + srow * 72 + sg * 8;
      *(bf16x8*)vd = *(const bf16x8*)vs;
      *(bf16x8*)(vd + 8) = *(const bf16x8*)(vs + 8);
    }
    __syncthreads();
    if (kbase > qw + 31) continue;                       // wave fully masked

    bf16x8 kf[4][2];                                     // A-frags: rows = keys
#pragma unroll
    for (int m = 0; m < 4; ++m) {
      kf[m][0] = *(const bf16x8*)(kbuf + (m * 16 + col) * 72 + quad * 8);
      kf[m][1] = *(const bf16x8*)(kbuf + (m * 16 + col) * 72 + 32 + quad * 8);
    }
#pragma unroll
    for (int nt = 0; nt < 2; ++nt) {
      const int qmin = qw + nt * 16;
      const int qtop = qmin + 15;
      if (kbase > qtop) continue;
      const int q = qmin + col;
#pragma unroll
      for (int m = 0; m < 4; ++m) {
        const int kb2 = kbase + m * 16;
        s16x4 pk;
        if (kb2 > qtop) {                                // fully above diagonal: p == 0
          pk[0] = 0; pk[1] = 0; pk[2] = 0; pk[3] = 0;
          *(s16x4*)(pbuf + (nt * 16 + col) * 72 + m * 16 + quad * 4) = pk;
          continue;
        }
        f32x4 sacc = (f32x4){0.f, 0.f, 0.f, 0.f};
        sacc = __builtin_amdgcn_mfma_f32_16x16x32_bf16(kf[m][0], qf[nt][0], sacc, 0, 0, 0);
        sacc = __builtin_amdgcn_mfma_f32_16x16x32_bf16(kf[m][1], qf[nt][1], sacc, 0, 0, 0);
        float ls = 0.f;
        if (kb2 + 15 <= qmin) {                          // fully below diagonal: no mask
#pragma unroll
          for (int r = 0; r < 4; ++r) {
            const float px = __builtin_amdgcn_exp2f(sacc[r] - EXP_BIAS);
            ls += px;
            pk[r] = (short)f2bf(px);
          }
        } else {                                         // diagonal block: per-element mask
#pragma unroll
          for (int r = 0; r < 4; ++r) {
            const int key = kb2 + quad * 4 + r;
            const float px = __builtin_amdgcn_exp2f(sacc[r] - EXP_BIAS);
            const float p = (key <= q) ? px : 0.f;
            ls += p;
            pk[r] = (short)f2bf(p);
          }
        }
        l[nt] += ls;
        *(s16x4*)(pbuf + (nt * 16 + col) * 72 + m * 16 + quad * 4) = pk;
      }
    }
    // PV: O^T += V^T · P^T
#pragma unroll
    for (int ch = 0; ch < 2; ++ch) {
      if (kbase + ch * 32 > qw + 31) continue;
      bf16x8 vf[4];
#pragma unroll
      for (int m = 0; m < 4; ++m)
        vf[m] = *(const bf16x8*)(vbuf + (m * 16 + col) * 72 + ch * 32 + quad * 8);
#pragma unroll
      for (int nt = 0; nt < 2; ++nt) {
        if (kbase + ch * 32 > qw + nt * 16 + 15) continue;
        const bf16x8 pf = *(const bf16x8*)(pbuf + (nt * 16 + col) * 72 + ch * 32 + quad * 8);
#pragma unroll
        for (int m = 0; m < 4; ++m)
          oacc[nt][m] = __builtin_amdgcn_mfma_f32_16x16x32_bf16(vf[m], pf, oacc[nt][m], 0, 0, 0);
      }
    }
  }

  // partial l: reduce across quads; lanes 0..15 hold cols 0..15
#pragma unroll
  for (int nt = 0; nt < 2; ++nt) {
    float v = l[nt];
    v += __shfl_xor(v, 16, 64);
    v += __shfl_xor(v, 32, 64);
    if (lane < 16) lp[h * 2048 + qw + nt * 16 + lane] = v;
  }

  // partial O^T numerator (fp32, un-normalized): float4 per (nt, m)
#pragma unroll
  for (int nt = 0; nt < 2; ++nt)
#pragma unroll
    for (int m = 0; m < 4; ++m)
      *(f32x4*)(Op + (size_t)(qw + nt * 16 + col) * 4544 + h * 64 + m * 16 + quad * 4) = oacc[nt][m];
}

// ---------- merge partials: O = (O0 [+O1]) / (l0 [+l1]) -> bf16; store invl ----------
__global__ __launch_bounds__(256) void attn_merge(
    const float* __restrict__ Op0, const float* __restrict__ Op1,
    const float* __restrict__ lp0, const float* __restrict__ lp1,
    ushort_t* __restrict__ merged, float* __restrict__ LI) {
  const int i = blockIdx.x * 256 + threadIdx.x;          // 8 floats per thread
  if (i >= 2048 * 4544 / 8) return;
  const int q = i / 568;                                 // 4544/8 = 568
  const int c = (i - q * 568) * 8;
  const int h = c >> 6;                                  // c..c+7 same head (c%8==0)
  const int dual = q >> 10;                              // q >= 1024 <=> qb >= 8
  float l = lp0[h * 2048 + q];
  if (dual) l += lp1[h * 2048 + q];
  const float invl = 1.0f / l;
  const float4* p0 = (const float4*)(Op0 + (size_t)q * 4544 + c);
  float4 a = p0[0], b = p0[1];
  if (dual) {
    const float4* p1 = (const float4*)(Op1 + (size_t)q * 4544 + c);
    float4 a1 = p1[0], b1 = p1[1];
    a.x += a1.x; a.y += a1.y; a.z += a1.z; a.w += a1.w;
    b.x += b1.x; b.y += b1.y; b.z += b1.z; b.w += b1.w;
  }
  bf16x8 v;
  v[0] = (short)f2bf(a.x * invl); v[1] = (short)f2bf(a.y * invl);
  v[2] = (short)f2bf(a.z * invl); v[3] = (short)f2bf(a.w * invl);
  v[4] = (short)f2bf(b.x * invl); v[5] = (short)f2bf(b.y * invl);
  v[6] = (short)f2bf(b.z * invl); v[7] = (short)f2bf(b.w * invl);
  *((bf16x8*)merged + i) = v;
  if ((c & 63) == 0) LI[h * 2048 + q] = invl;
}

// ---------- sweep 2: normalized colsums, KV-SPLIT (keys < 1920) ----------
// Block = 128 q x 1 head x <=8 key tiles; splits per qb: 1+qb/4 (40 blocks/head).
__global__ __launch_bounds__(256) void attn_colsum(
    const ushort_t* __restrict__ Qr, const ushort_t* __restrict__ Kr,
    const float* __restrict__ LI, float* __restrict__ ssum) {
  const int bx = blockIdx.x;
  const int h = blockIdx.y;
  int qb, si, nsp;
  if (bx < 16)      { nsp = 4; qb = 15 - (bx >> 2); si = bx & 3; }
  else if (bx < 28) { nsp = 3; const int r = bx - 16; qb = 11 - r / 3; si = r % 3; }
  else if (bx < 36) { nsp = 2; const int r = bx - 28; qb = 7 - (r >> 1); si = r & 1; }
  else              { nsp = 1; qb = 39 - bx; si = 0; }
  const int nt2 = min((qb + 1) * 2, 30);
  const int kt0 = (nt2 * si) / nsp, kt1 = (nt2 * (si + 1)) / nsp;
  const int q0 = qb * 128;
  const int tid = threadIdx.x, wave = tid >> 6, lane = tid & 63;
  const int quad = lane >> 4, col = lane & 15;
  const int qw = q0 + wave * 32;

  __shared__ __align__(16) ushort_t kbuf[64 * 72];
  __shared__ float cs[512];

  const int c0 = tid * 2;
  const int srow = c0 >> 3, sg = c0 & 7;

  bf16x8 qf[2][2];
#pragma unroll
  for (int i = 0; i < 2; ++i)
#pragma unroll
    for (int s = 0; s < 2; ++s)
      qf[i][s] = *(const bf16x8*)(Qr + (size_t)(qw + i * 16 + col) * 4544 + h * 64 + s * 32 + quad * 8);

  float linv2[2][4];
#pragma unroll
  for (int i = 0; i < 2; ++i)
#pragma unroll
    for (int r = 0; r < 4; ++r)
      linv2[i][r] = LI[h * 2048 + qw + i * 16 + quad * 4 + r];

  const int cov = (kt1 - kt0) * 64;
  for (int j = tid; j < cov; j += 256) cs[j] = 0.f;

  for (int t = kt0; t < kt1; ++t) {
    const int kbase = t * 64;
    __syncthreads();                                 // orders cs zeroing too (t==kt0)
    {
      const ushort_t* ks = Kr + (size_t)(kbase + srow) * 64 + sg * 8;
      ushort_t* kd = kbuf + srow * 72 + sg * 8;
      *(bf16x8*)kd = *(const bf16x8*)ks;
      *(bf16x8*)(kd + 8) = *(const bf16x8*)(ks + 8);
    }
    __syncthreads();
    if (kbase > qw + 31) continue;

    bf16x8 kf[4][2];
#pragma unroll
    for (int n = 0; n < 4; ++n) {
      kf[n][0] = *(const bf16x8*)(kbuf + (n * 16 + col) * 72 + quad * 8);
      kf[n][1] = *(const bf16x8*)(kbuf + (n * 16 + col) * 72 + 32 + quad * 8);
    }
    float accn[4] = {0.f, 0.f, 0.f, 0.f};
#pragma unroll
    for (int i = 0; i < 2; ++i) {
      const int qmin = qw + i * 16;
      const int qmax = qmin + 15;
      if (kbase > qmax) continue;
#pragma unroll
      for (int n = 0; n < 4; ++n) {
        const int kb2 = kbase + n * 16;
        if (kb2 > qmax) continue;
        f32x4 sacc = __builtin_amdgcn_mfma_f32_16x16x32_bf16(qf[i][0], kf[n][0],
                       (f32x4){0.f, 0.f, 0.f, 0.f}, 0, 0, 0);
        sacc = __builtin_amdgcn_mfma_f32_16x16x32_bf16(qf[i][1], kf[n][1], sacc, 0, 0, 0);
        if (kb2 + 15 <= qmin) {
#pragma unroll
          for (int r = 0; r < 4; ++r)
            accn[n] += __builtin_amdgcn_exp2f(sacc[r] - EXP_BIAS) * linv2[i][r];
        } else {
#pragma unroll
          for (int r = 0; r < 4; ++r) {
            const int q = qmin + quad * 4 + r;
            const int key = kb2 + col;
            const float px = __builtin_amdgcn_exp2f(sacc[r] - EXP_BIAS) * linv2[i][r];
            accn[n] += (key <= q) ? px : 0.f;
          }
        }
      }
    }
#pragma unroll
    for (int n = 0; n < 4; ++n) {
      float v = accn[n];
      v += __shfl_xor(v, 16, 64);
      v += __shfl_xor(v, 32, 64);
      if (quad == 0) atomicAdd(&cs[kbase - kt0 * 64 + n * 16 + col], v);
    }
  }

  __syncthreads();
  for (int j = tid; j < cov; j += 256) atomicAdd(&ssum[kt0 * 64 + j], cs[j]);
}

// ---------- fallback monolithic attn (r3, verified) ----------
__global__ __launch_bounds__(256) void attn_flash(
    const ushort_t* __restrict__ Qr, const ushort_t* __restrict__ Kr,
    const ushort_t* __restrict__ Vt, ushort_t* __restrict__ merged,
    float* __restrict__ ssum) {
  const int qb = (int)gridDim.x - 1 - (int)blockIdx.x;
  const int h = blockIdx.y;
  const int q0 = qb * 128;
  const int tid = threadIdx.x, wave = tid >> 6, lane = tid & 63;
  const int quad = lane >> 4, col = lane & 15;
  const int qw = q0 + wave * 32;
  const int ntiles = (qb + 1) * 2;

  __shared__ __align__(16) ushort_t kbuf[64 * 72];
  __shared__ __align__(16) ushort_t vbuf[64 * 72];
  __shared__ __align__(16) char pcs[4 * 32 * 72 * 2];
  ushort_t* pbuf = (ushort_t*)pcs + wave * (32 * 72);
  float* cs = (float*)pcs;

  const int c0 = tid * 2;
  const int srow = c0 >> 3, sg = c0 & 7;

  bf16x8 qf[2][2];
#pragma unroll
  for (int nt = 0; nt < 2; ++nt)
#pragma unroll
    for (int s = 0; s < 2; ++s)
      qf[nt][s] = *(const bf16x8*)(Qr + (size_t)(qw + nt * 16 + col) * 4544 + h * 64 + s * 32 + quad * 8);

  f32x4 oacc[2][4];
  float l[2] = {0.f, 0.f};
#pragma unroll
  for (int nt = 0; nt < 2; ++nt)
#pragma unroll
    for (int m = 0; m < 4; ++m) oacc[nt][m] = (f32x4){0.f, 0.f, 0.f, 0.f};

  for (int t = 0; t < ntiles; ++t) {
    const int kbase = t * 64;
    __syncthreads();
    {
      const ushort_t* ks = Kr + (size_t)(kbase + srow) * 64 + sg * 8;
      ushort_t* kd = kbuf + srow * 72 + sg * 8;
      *(bf16x8*)kd = *(const bf16x8*)ks;
      *(bf16x8*)(kd + 8) = *(const bf16x8*)(ks + 8);
      const ushort_t* vs = Vt + (size_t)srow * 2048 + kbase + sg * 8;
      ushort_t* vd = vbuf + srow * 72 + sg * 8;
      *(bf16x8*)vd = *(const bf16x8*)vs;
      *(bf16x8*)(vd + 8) = *(const bf16x8*)(vs + 8);
    }
    __syncthreads();
    if (kbase > qw + 31) continue;

    bf16x8 kf[4][2];
#pragma unroll
    for (int m = 0; m < 4; ++m) {
      kf[m][0] = *(const bf16x8*)(kbuf + (m * 16 + col) * 72 + quad * 8);
      kf[m][1] = *(const bf16x8*)(kbuf + (m * 16 + col) * 72 + 32 + quad * 8);
    }
#pragma unroll
    for (int nt = 0; nt < 2; ++nt) {
      const int qmin = qw + nt * 16;
      const int qtop = qmin + 15;
      if (kbase > qtop) continue;
      const int q = qmin + col;
#pragma unroll
      for (int m = 0; m < 4; ++m) {
        const int kb2 = kbase + m * 16;
        s16x4 pk;
        if (kb2 > qtop) {
          pk[0] = 0; pk[1] = 0; pk[2] = 0; pk[3] = 0;
          *(s16x4*)(pbuf + (nt * 16 + col) * 72 + m * 16 + quad * 4) = pk;
          continue;
        }
        f32x4 sacc = (f32x4){0.f, 0.f, 0.f, 0.f};
        sacc = __builtin_amdgcn_mfma_f32_16x16x32_bf16(kf[m][0], qf[nt][0], sacc, 0, 0, 0);
        sacc = __builtin_amdgcn_mfma_f32_16x16x32_bf16(kf[m][1], qf[nt][1], sacc, 0, 0, 0);
        float ls = 0.f;
        if (kb2 + 15 <= qmin) {
#pragma unroll
          for (int r = 0; r < 4; ++r) {
            const float px = __builtin_amdgcn_exp2f(sacc[r] - EXP_BIAS);
            ls += px;
            pk[r] = (short)f2bf(px);
          }
        } else {
#pragma unroll
          for (int r = 0; r < 4; ++r) {
            const int key = kb2 + quad * 4 + r;
            const float px = __builtin_amdgcn_exp2f(sacc[r] - EXP_BIAS);
            const float p = (key <= q) ? px : 0.f;
            ls += p;
            pk[r] = (short)f2bf(p);
          }
        }
        l[nt] += ls;
        *(s16x4*)(pbuf + (nt * 16 + col) * 72 + m * 16 + quad * 4) = pk;
      }
    }
#pragma unroll
    for (int ch = 0; ch < 2; ++ch) {
      if (kbase + ch * 32 > qw + 31) continue;
      bf16x8 vf[4];
#pragma unroll
      for (int m = 0; m < 4; ++m)
        vf[m] = *(const bf16x8*)(vbuf + (m * 16 + col) * 72 + ch * 32 + quad * 8);
#pragma unroll
      for (int nt = 0; nt < 2; ++nt) {
        if (kbase + ch * 32 > qw + nt * 16 + 15) continue;
        const bf16x8 pf = *(const bf16x8*)(pbuf + (nt * 16 + col) * 72 + ch * 32 + quad * 8);
#pragma unroll
        for (int m = 0; m < 4; ++m)
          oacc[nt][m] = __builtin_amdgcn_mfma_f32_16x16x32_bf16(vf[m], pf, oacc[nt][m], 0, 0, 0);
      }
    }
  }

  float invl[2];
#pragma unroll
  for (int nt = 0; nt < 2; ++nt) {
    float v = l[nt];
    v += __shfl_xor(v, 16, 64);
    v += __shfl_xor(v, 32, 64);
    invl[nt] = 1.0f / v;
  }

#pragma unroll
  for (int nt = 0; nt < 2; ++nt)
#pragma unroll
    for (int m = 0; m < 4; ++m) {
      s16x4 ok;
#pragma unroll
      for (int r = 0; r < 4; ++r) ok[r] = (short)f2bf(oacc[nt][m][r] * invl[nt]);
      *(s16x4*)(merged + (size_t)(qw + nt * 16 + col) * 4544 + h * 64 + m * 16 + quad * 4) = ok;
    }

  float linv2[2][4];
#pragma unroll
  for (int i = 0; i < 2; ++i)
#pragma unroll
    for (int r = 0; r < 4; ++r) linv2[i][r] = __shfl(invl[i], quad * 4 + r, 16);

  __syncthreads();
  const int nk2 = min(ntiles * 64, 1920);
  const int nt2 = min(ntiles, 30);
  for (int j = tid; j < nk2; j += 256) cs[j] = 0.f;

  for (int t = 0; t < nt2; ++t) {
    const int kbase = t * 64;
    __syncthreads();
    {
      const ushort_t* ks = Kr + (size_t)(kbase + srow) * 64 + sg * 8;
      ushort_t* kd = kbuf + srow * 72 + sg * 8;
      *(bf16x8*)kd = *(const bf16x8*)ks;
      *(bf16x8*)(kd + 8) = *(const bf16x8*)(ks + 8);
    }
    __syncthreads();
    if (kbase > qw + 31) continue;

    bf16x8 kf[4][2];
#pragma unroll
    for (int n = 0; n < 4; ++n) {
      kf[n][0] = *(const bf16x8*)(kbuf + (n * 16 + col) * 72 + quad * 8);
      kf[n][1] = *(const bf16x8*)(kbuf + (n * 16 + col) * 72 + 32 + quad * 8);
    }
    float accn[4] = {0.f, 0.f, 0.f, 0.f};
#pragma unroll
    for (int i = 0; i < 2; ++i) {
      const int qmin = qw + i * 16;
      const int qmax = qmin + 15;
      if (kbase > qmax) continue;
#pragma unroll
      for (int n = 0; n < 4; ++n) {
        const int kb2 = kbase + n * 16;
        if (kb2 > qmax) continue;
        f32x4 sacc = __builtin_amdgcn_mfma_f32_16x16x32_bf16(qf[i][0], kf[n][0],
                       (f32x4){0.f, 0.f, 0.f, 0.f}, 0, 0, 0);
        sacc = __builtin_amdgcn_mfma_f32_16x16x32_bf16(qf[i][1], kf[n][1], sacc, 0, 0, 0);
        if (kb2 + 15 <= qmin) {
#pragma unroll
          for (int r = 0; r < 4; ++r)
            accn[n] += __builtin_amdgcn_exp2f(sacc[r] - EXP_BIAS) * linv2[i][r];
        } else {
#pragma unroll
          for (int r = 0; r < 4; ++r) {
            const int q = qmin + quad * 4 + r;
            const int key = kb2 + col;
            const float px = __builtin_amdgcn_exp2f(sacc[r] - EXP_BIAS) * linv2[i][r];
            accn[n] += (key <= q) ? px : 0.f;
          }
        }
      }
    }
#pragma unroll
    for (int n = 0; n < 4; ++n) {
      float v = accn[n];
      v += __shfl_xor(v, 16, 64);
      v += __shfl_xor(v, 32, 64);
      if (quad == 0) atomicAdd(&cs[kbase + n * 16 + col], v);
    }
  }

  __syncthreads();
  for (int j = tid; j < nk2; j += 256) atomicAdd(&ssum[j], cs[j]);
}

// ---------- top-k(128) of ssum[0..1919] -> mask (2049 floats) ----------
__global__ __launch_bounds__(1024) void topk_mask(
    const float* __restrict__ ssum, float* __restrict__ maskout) {
  __shared__ float sv[1920];
  for (int i = threadIdx.x; i < 1920; i += 1024) sv[i] = ssum[i];
  __syncthreads();
  for (int i = threadIdx.x; i < 2049; i += 1024) {
    float o;
    if (i >= 1921) o = 1.f;
    else if (i == 1920) o = 0.f;
    else {
      const float v = sv[i];
      int rank = 0;
      for (int j = 0; j < 1920; ++j) {
        const float w = sv[j];
        rank += (w > v) || (w == v && j < i);
      }
      o = (rank < 128) ? 1.f : 0.f;
    }
    maskout[i] = o;
  }
}

// ---------- launch ----------
extern "C" void kernel_launch(void* const* d_in, const int* in_sizes, int n_in,
                              void* d_out, int out_size, void* d_ws, size_t ws_size,
                              hipStream_t stream) {
  (void)in_sizes; (void)n_in; (void)out_size;
  const float* hs      = (const float*)d_in[0];   // 1x2048x4544
  const float* w_qkv   = (const float*)d_in[1];   // 4544x4672
  const float* w_dense = (const float*)d_in[2];   // 4544x4544
  float* out = (float*)d_out;                     // 2048*4544 + 2049

  char* ws = (char*)d_ws;
  constexpr size_t OFF_WT    = 0;                        // 4736x4544 bf16
  constexpr size_t OFF_HSB   = 43040768;                 // 2048x4544 bf16 (reused as merged)
  constexpr size_t OFF_FUSED = OFF_HSB + 18612224;       // 2048x4672 fp32 (reused as Opart0)
  constexpr size_t OFF_QR    = OFF_FUSED + 38273024;     // 2048x4544 bf16
  constexpr size_t OFF_KR    = OFF_QR + 18612224;        // 2048x64 bf16
  constexpr size_t OFF_VT    = OFF_KR + 262144;          // 64x2048 bf16
  constexpr size_t OFF_SS    = OFF_VT + 262144;          // 2048 fp32
  constexpr size_t OFF_F2    = OFF_SS + 8192;            // 2048x4672 fp32 (split-K C1 / Opart1)
  constexpr size_t OFF_LP0   = OFF_F2 + 38273024;        // 71x2048 fp32
  constexpr size_t OFF_LP1   = OFF_LP0 + 581632;         // 71x2048 fp32
  constexpr size_t OFF_LI    = OFF_LP1 + 581632;         // 71x2048 fp32
  constexpr size_t WS_NEED   = OFF_LI + 581632;          // ~151.7 MiB

  ushort_t* wT     = (ushort_t*)(ws + OFF_WT);
  ushort_t* hsb    = (ushort_t*)(ws + OFF_HSB);
  float*    fused  = (float*)(ws + OFF_FUSED);
  ushort_t* qr     = (ushort_t*)(ws + OFF_QR);
  ushort_t* kr     = (ushort_t*)(ws + OFF_KR);
  ushort_t* vt     = (ushort_t*)(ws + OFF_VT);
  float*    ssum   = (float*)(ws + OFF_SS);
  float*    fused1 = (float*)(ws + OFF_F2);
  float*    lp0    = (float*)(ws + OFF_LP0);
  float*    lp1    = (float*)(ws + OFF_LP1);
  float*    li     = (float*)(ws + OFF_LI);

  const int split = (ws_size >= WS_NEED) ? 1 : 0;        // fall back if ws too small

  f32_to_bf16_vec<<<4544, 256, 0, stream>>>(hs, hsb, 2048 * 4544 / 8);
  transpose_w_bf16<<<dim3(148, 142), 256, 0, stream>>>(w_qkv, wT, 4672, 4544);
  if (split) {
    gemm_bt_128<<<dim3(32, 37), 256, 0, stream>>>(hsb, wT, fused, fused1, 4672, 4544, 4672, 1);
    rope_split<<<2048, 256, 0, stream>>>(fused, fused1, 1, qr, kr, vt, ssum);
  } else {
    gemm_bt_128<<<dim3(16, 37), 256, 0, stream>>>(hsb, wT, fused, fused, 4672, 4544, 4672, 0);
    rope_split<<<2048, 256, 0, stream>>>(fused, fused, 0, qr, kr, vt, ssum);
  }
  transpose_w_bf16<<<dim3(144, 142), 256, 0, stream>>>(w_dense, wT, 4544, 4544);
  if (split) {
    attn_sweep1<<<dim3(24, 71), 256, 0, stream>>>(qr, kr, vt, fused, fused1, lp0, lp1);
    attn_merge<<<4544, 256, 0, stream>>>(fused, fused1, lp0, lp1, hsb, li);
    attn_colsum<<<dim3(40, 71), 256, 0, stream>>>(qr, kr, li, ssum);
  } else {
    attn_flash<<<dim3(16, 71), 256, 0, stream>>>(qr, kr, vt, hsb, ssum);
  }
  topk_mask<<<1, 1024, 0, stream>>>(ssum, out + (size_t)2048 * 4544);
  if (split) {
    gemm_bt_128<<<dim3(32, 36), 256, 0, stream>>>(hsb, wT, out, fused1, 4544, 4544, 4544, 1);
    add_inplace_f4<<<9088, 256, 0, stream>>>(out, fused1, 2048 * 4544 / 4);
  } else {
    gemm_bt_128<<<dim3(16, 36), 256, 0, stream>>>(hsb, wT, out, out, 4544, 4544, 4544, 0);
  }
}

// Round 6
// 717.225 us; speedup vs baseline: 1.3901x; 1.1171x over previous
//
#include <hip/hip_runtime.h>

typedef __attribute__((ext_vector_type(8))) short bf16x8;
typedef __attribute__((ext_vector_type(4))) short s16x4;
typedef __attribute__((ext_vector_type(4))) float f32x4;
typedef unsigned short ushort_t;

#define LOG2E 1.44269504088896340736f
#define EXP_BIAS 23.08312066f          /* 16 * LOG2E */
#define Q_SCALE 0.18033688f            /* 0.125 * LOG2E */

// ---------- helpers ----------
__device__ __forceinline__ unsigned short f2bf(float x) {
  unsigned int u = __float_as_uint(x);
  u = (u + 0x7FFFu + ((u >> 16) & 1u)) >> 16;   // RNE
  return (unsigned short)u;
}

__device__ __forceinline__ void async16(void* lds_dst, const void* gsrc) {
  __builtin_amdgcn_global_load_lds(
      (const __attribute__((address_space(1))) void*)gsrc,
      (__attribute__((address_space(3))) void*)lds_dst, 16, 0, 0);
}

// ---------- fp32 -> bf16 row-major (vectorized) ----------
__global__ __launch_bounds__(256) void f32_to_bf16_vec(
    const float* __restrict__ in, ushort_t* __restrict__ out, int n8) {
  int i = blockIdx.x * 256 + threadIdx.x;
  if (i >= n8) return;
  const float4* p = (const float4*)in + (size_t)i * 2;
  float4 a = p[0], b = p[1];
  bf16x8 v;
  v[0] = (short)f2bf(a.x); v[1] = (short)f2bf(a.y);
  v[2] = (short)f2bf(a.z); v[3] = (short)f2bf(a.w);
  v[4] = (short)f2bf(b.x); v[5] = (short)f2bf(b.y);
  v[6] = (short)f2bf(b.z); v[7] = (short)f2bf(b.w);
  *((bf16x8*)out + i) = v;
}

// ---------- transpose fp32 (Kd x N) -> bf16 (Npad x Kd), zero-pad rows >= N ----------
__global__ __launch_bounds__(256) void transpose_w_bf16(
    const float* __restrict__ in, ushort_t* __restrict__ out, int N, int Kd) {
  __shared__ float tile[32][33];
  const int tx = threadIdx.x & 31, ty = threadIdx.x >> 5;
  const int n0 = blockIdx.x * 32, k0 = blockIdx.y * 32;
#pragma unroll
  for (int yy = 0; yy < 32; yy += 8) {
    int k = k0 + ty + yy;
    int n = n0 + tx;
    tile[ty + yy][tx] = (n < N) ? in[(size_t)k * N + n] : 0.f;
  }
  __syncthreads();
#pragma unroll
  for (int yy = 0; yy < 32; yy += 8) {
    int n = n0 + ty + yy;
    int k = k0 + tx;
    out[(size_t)n * Kd + k] = f2bf(tile[tx][ty + yy]);
  }
}

// ---------- 128x128-tile bf16 GEMM, BK=64, C = A(MxK) @ Bt(NpadxK)^T, fp32 out ----------
// split==1: blockIdx.x&1 selects K-half (2304/2240, both %64==0) and output
// buffer (C0 or C1); halves summed by the CONSUMER (no atomics, no zeroing).
__global__ __launch_bounds__(256) void gemm_bt_128(
    const ushort_t* __restrict__ A, const ushort_t* __restrict__ Bt,
    float* __restrict__ C0, float* __restrict__ C1,
    int N, int K, int ldc, int split) {
  __shared__ __align__(16) char lds[32768];  // half0: A[0,8K) B[8K,16K); half1: +16K
  const int tid = threadIdx.x;
  const int lane = tid & 63, wave = tid >> 6;
  const int quad = lane >> 4, col = lane & 15;
  const int bm = split ? ((int)blockIdx.x >> 1) : (int)blockIdx.x;
  const int half = split ? ((int)blockIdx.x & 1) : 0;
  const int bn = blockIdx.y;
  float* __restrict__ C = half ? C1 : C0;
  int ks, ke;
  if (split) {
    const int s0 = ((((K >> 6) + 1) >> 1) << 6);         // 2304 for K=4544
    ks = half ? s0 : 0;
    ke = half ? K : s0;
  } else { ks = 0; ke = K; }
  const int wr = (wave >> 1) * 64, wc = (wave & 1) * 64;

  const int c0 = tid, c1 = tid + 256;
  const int r0 = c0 >> 2, r1 = c1 >> 2;
  const int l0 = (c0 & 3) ^ ((r0 >> 1) & 3);
  const int l1 = (c1 & 3) ^ ((r1 >> 1) & 3);
  const ushort_t* a0 = A + (size_t)(bm * 128 + r0) * K + l0 * 8;
  const ushort_t* a1 = A + (size_t)(bm * 128 + r1) * K + l1 * 8;
  const ushort_t* b0 = Bt + (size_t)(bn * 128 + r0) * K + l0 * 8;
  const ushort_t* b1 = Bt + (size_t)(bn * 128 + r1) * K + l1 * 8;
  const int wb = wave * 1024;

  f32x4 acc[4][4];
#pragma unroll
  for (int i = 0; i < 4; ++i)
#pragma unroll
    for (int j = 0; j < 4; ++j) acc[i][j] = (f32x4){0.f, 0.f, 0.f, 0.f};

  const int ccsw = (col >> 1) & 3;
  int aoff[4], boff[4];
#pragma unroll
  for (int t = 0; t < 4; ++t) {
    aoff[t] = (wr + t * 16 + col) * 64 + ((quad ^ ccsw) << 4);
    boff[t] = 8192 + (wc + t * 16 + col) * 64 + ((quad ^ ccsw) << 4);
  }

#pragma unroll 1
  for (int k = ks; k < ke; k += 64) {
    __syncthreads();
    async16(lds + wb,                   a0 + k);
    async16(lds + wb + 4096,            a1 + k);
    async16(lds + 8192 + wb,            b0 + k);
    async16(lds + 8192 + wb + 4096,     b1 + k);
    async16(lds + 16384 + wb,           a0 + k + 32);
    async16(lds + 16384 + wb + 4096,    a1 + k + 32);
    async16(lds + 24576 + wb,           b0 + k + 32);
    async16(lds + 24576 + wb + 4096,    b1 + k + 32);
    __syncthreads();
#pragma unroll
    for (int kk = 0; kk < 2; ++kk) {
      const char* base = lds + kk * 16384;
      bf16x8 af[4], bfr[4];
#pragma unroll
      for (int t = 0; t < 4; ++t) {
        af[t]  = *(const bf16x8*)(base + aoff[t]);
        bfr[t] = *(const bf16x8*)(base + boff[t]);
      }
#pragma unroll
      for (int i = 0; i < 4; ++i)
#pragma unroll
        for (int j = 0; j < 4; ++j)
          acc[i][j] = __builtin_amdgcn_mfma_f32_16x16x32_bf16(af[i], bfr[j], acc[i][j], 0, 0, 0);
    }
  }

#pragma unroll
  for (int i = 0; i < 4; ++i) {
    const int row = bm * 128 + wr + i * 16 + quad * 4;
#pragma unroll
    for (int j = 0; j < 4; ++j) {
      const int cc = bn * 128 + wc + j * 16 + col;
      if (cc < N) {
#pragma unroll
        for (int r = 0; r < 4; ++r)
          C[(size_t)(row + r) * ldc + cc] = acc[i][j][r];
      }
    }
  }
}

// ---------- out[i] += src[i], float4 ----------
__global__ __launch_bounds__(256) void add_inplace_f4(
    float* __restrict__ dst, const float* __restrict__ src, int n4) {
  int i = blockIdx.x * 256 + threadIdx.x;
  if (i >= n4) return;
  float4 a = ((const float4*)dst)[i];
  float4 b = ((const float4*)src)[i];
  a.x += b.x; a.y += b.y; a.z += b.z; a.w += b.w;
  ((float4*)dst)[i] = a;
}

// ---------- RoPE + split fused(2048x4672) -> Qr(/8*log2e, bf16), Kr, Vt; zero ssum ----------
__global__ __launch_bounds__(256) void rope_split(
    const float* __restrict__ f0, const float* __restrict__ f1, int two,
    ushort_t* __restrict__ Qr, ushort_t* __restrict__ Kr,
    ushort_t* __restrict__ Vt, float* __restrict__ ssum) {
  const int spos = blockIdx.x;
  const float* row0 = f0 + (size_t)spos * 4672;
  const float* row1 = f1 + (size_t)spos * 4672;
  if (blockIdx.x == 0)
    for (int j = threadIdx.x; j < 2048; j += 256) ssum[j] = 0.f;
  for (int c = threadIdx.x; c < 4672; c += 256) {
    const int hh = c >> 6, d = c & 63, j = d & 31;
    const float x = two ? (row0[c] + row1[c]) : row0[c];
    if (hh == 72) { Vt[(size_t)d * 2048 + spos] = f2bf(x); continue; }
    const float freq = __builtin_amdgcn_exp2f((float)j * -0.41524101186f);
    const float ang = (float)spos * freq;
    float sv, cv;
    __sincosf(ang, &sv, &cv);
    const int cp = (d < 32) ? c + 32 : c - 32;
    const float partner = two ? (row0[cp] + row1[cp]) : row0[cp];
    const float val = (d < 32) ? (x * cv - partner * sv) : (x * cv + partner * sv);
    if (hh == 71) Kr[(size_t)spos * 64 + d] = f2bf(val);
    else          Qr[(size_t)spos * 4544 + c] = f2bf(val * Q_SCALE);
  }
}

// ---------- attention sweep 1, KV-SPLIT partials ----------
// Fixed-base softmax (p = exp2(s - bias), NO running max) => partial numerator
// O and denominator l over disjoint key ranges merge by pure addition.
// Block = 128 q x 1 head x key-tile range [kt0,kt1). qb>=8 split into two
// halves (<=16 tiles; low half provably fully-unmasked), qb<8 unsplit.
__global__ __launch_bounds__(256) void attn_sweep1(
    const ushort_t* __restrict__ Qr, const ushort_t* __restrict__ Kr,
    const ushort_t* __restrict__ Vt, float* __restrict__ Op0,
    float* __restrict__ Op1, float* __restrict__ lp0, float* __restrict__ lp1) {
  const int bx = blockIdx.x;
  const int h = blockIdx.y;
  int qb, kt0, kt1, buf1;
  if (bx < 8)       { qb = 15 - bx;       kt0 = 0;      kt1 = qb + 1;       buf1 = 0; }
  else if (bx < 16) { qb = 15 - (bx - 8); kt0 = qb + 1; kt1 = (qb + 1) * 2; buf1 = 1; }
  else              { qb = 23 - bx;       kt0 = 0;      kt1 = (qb + 1) * 2; buf1 = 0; }
  float* __restrict__ Op = buf1 ? Op1 : Op0;
  float* __restrict__ lp = buf1 ? lp1 : lp0;
  const int q0 = qb * 128;
  const int tid = threadIdx.x, wave = tid >> 6, lane = tid & 63;
  const int quad = lane >> 4, col = lane & 15;
  const int qw = q0 + wave * 32;

  __shared__ __align__(16) ushort_t kbuf[64 * 72];
  __shared__ __align__(16) ushort_t vbuf[64 * 72];
  __shared__ __align__(16) ushort_t pbuf_s[4 * 32 * 72];
  ushort_t* pbuf = pbuf_s + wave * (32 * 72);            // P^T: [32 q][64 k] stride 72

  const int c0 = tid * 2;
  const int srow = c0 >> 3, sg = c0 & 7;

  bf16x8 qf[2][2];
#pragma unroll
  for (int nt = 0; nt < 2; ++nt)
#pragma unroll
    for (int s = 0; s < 2; ++s)
      qf[nt][s] = *(const bf16x8*)(Qr + (size_t)(qw + nt * 16 + col) * 4544 + h * 64 + s * 32 + quad * 8);

  f32x4 oacc[2][4];
  float l[2] = {0.f, 0.f};
#pragma unroll
  for (int nt = 0; nt < 2; ++nt)
#pragma unroll
    for (int m = 0; m < 4; ++m) oacc[nt][m] = (f32x4){0.f, 0.f, 0.f, 0.f};

  for (int t = kt0; t < kt1; ++t) {
    const int kbase = t * 64;
    __syncthreads();
    {
      const ushort_t* ks = Kr + (size_t)(kbase + srow) * 64 + sg * 8;
      ushort_t* kd = kbuf + srow * 72 + sg * 8;
      *(bf16x8*)kd = *(const bf16x8*)ks;
      *(bf16x8*)(kd + 8) = *(const bf16x8*)(ks + 8);
      const ushort_t* vs = Vt + (size_t)srow * 2048 + kbase + sg * 8;
      ushort_t* vd = vbuf + srow * 72 + sg * 8;
      *(bf16x8*)vd = *(const bf16x8*)vs;
      *(bf16x8*)(vd + 8) = *(const bf16x8*)(vs + 8);
    }
    __syncthreads();
    if (kbase > qw + 31) continue;                       // wave fully masked

    bf16x8 kf[4][2];                                     // A-frags: rows = keys
#pragma unroll
    for (int m = 0; m < 4; ++m) {
      kf[m][0] = *(const bf16x8*)(kbuf + (m * 16 + col) * 72 + quad * 8);
      kf[m][1] = *(const bf16x8*)(kbuf + (m * 16 + col) * 72 + 32 + quad * 8);
    }
#pragma unroll
    for (int nt = 0; nt < 2; ++nt) {
      const int qmin = qw + nt * 16;
      const int qtop = qmin + 15;
      if (kbase > qtop) continue;
      const int q = qmin + col;
#pragma unroll
      for (int m = 0; m < 4; ++m) {
        const int kb2 = kbase + m * 16;
        s16x4 pk;
        if (kb2 > qtop) {                                // fully above diagonal: p == 0
          pk[0] = 0; pk[1] = 0; pk[2] = 0; pk[3] = 0;
          *(s16x4*)(pbuf + (nt * 16 + col) * 72 + m * 16 + quad * 4) = pk;
          continue;
        }
        f32x4 sacc = (f32x4){0.f, 0.f, 0.f, 0.f};
        sacc = __builtin_amdgcn_mfma_f32_16x16x32_bf16(kf[m][0], qf[nt][0], sacc, 0, 0, 0);
        sacc = __builtin_amdgcn_mfma_f32_16x16x32_bf16(kf[m][1], qf[nt][1], sacc, 0, 0, 0);
        float ls = 0.f;
        if (kb2 + 15 <= qmin) {                          // fully below diagonal: no mask
#pragma unroll
          for (int r = 0; r < 4; ++r) {
            const float px = __builtin_amdgcn_exp2f(sacc[r] - EXP_BIAS);
            ls += px;
            pk[r] = (short)f2bf(px);
          }
        } else {                                         // diagonal block: per-element mask
#pragma unroll
          for (int r = 0; r < 4; ++r) {
            const int key = kb2 + quad * 4 + r;
            const float px = __builtin_amdgcn_exp2f(sacc[r] - EXP_BIAS);
            const float p = (key <= q) ? px : 0.f;
            ls += p;
            pk[r] = (short)f2bf(p);
          }
        }
        l[nt] += ls;
        *(s16x4*)(pbuf + (nt * 16 + col) * 72 + m * 16 + quad * 4) = pk;
      }
    }
    // PV: O^T += V^T · P^T
#pragma unroll
    for (int ch = 0; ch < 2; ++ch) {
      if (kbase + ch * 32 > qw + 31) continue;
      bf16x8 vf[4];
#pragma unroll
      for (int m = 0; m < 4; ++m)
        vf[m] = *(const bf16x8*)(vbuf + (m * 16 + col) * 72 + ch * 32 + quad * 8);
#pragma unroll
      for (int nt = 0; nt < 2; ++nt) {
        if (kbase + ch * 32 > qw + nt * 16 + 15) continue;
        const bf16x8 pf = *(const bf16x8*)(pbuf + (nt * 16 + col) * 72 + ch * 32 + quad * 8);
#pragma unroll
        for (int m = 0; m < 4; ++m)
          oacc[nt][m] = __builtin_amdgcn_mfma_f32_16x16x32_bf16(vf[m], pf, oacc[nt][m], 0, 0, 0);
      }
    }
  }

  // partial l: reduce across quads; lanes 0..15 hold cols 0..15
#pragma unroll
  for (int nt = 0; nt < 2; ++nt) {
    float v = l[nt];
    v += __shfl_xor(v, 16, 64);
    v += __shfl_xor(v, 32, 64);
    if (lane < 16) lp[h * 2048 + qw + nt * 16 + lane] = v;
  }

  // partial O^T numerator (fp32, un-normalized): float4 per (nt, m)
#pragma unroll
  for (int nt = 0; nt < 2; ++nt)
#pragma unroll
    for (int m = 0; m < 4; ++m)
      *(f32x4*)(Op + (size_t)(qw + nt * 16 + col) * 4544 + h * 64 + m * 16 + quad * 4) = oacc[nt][m];
}

// ---------- merge partials: O = (O0 [+O1]) / (l0 [+l1]) -> bf16; store invl ----------
__global__ __launch_bounds__(256) void attn_merge(
    const float* __restrict__ Op0, const float* __restrict__ Op1,
    const float* __restrict__ lp0, const float* __restrict__ lp1,
    ushort_t* __restrict__ merged, float* __restrict__ LI) {
  const int i = blockIdx.x * 256 + threadIdx.x;          // 8 floats per thread
  if (i >= 2048 * 4544 / 8) return;
  const int q = i / 568;                                 // 4544/8 = 568
  const int c = (i - q * 568) * 8;
  const int h = c >> 6;                                  // c..c+7 same head (c%8==0)
  const int dual = q >> 10;                              // q >= 1024 <=> qb >= 8
  float l = lp0[h * 2048 + q];
  if (dual) l += lp1[h * 2048 + q];
  const float invl = 1.0f / l;
  const float4* p0 = (const float4*)(Op0 + (size_t)q * 4544 + c);
  float4 a = p0[0], b = p0[1];
  if (dual) {
    const float4* p1 = (const float4*)(Op1 + (size_t)q * 4544 + c);
    float4 a1 = p1[0], b1 = p1[1];
    a.x += a1.x; a.y += a1.y; a.z += a1.z; a.w += a1.w;
    b.x += b1.x; b.y += b1.y; b.z += b1.z; b.w += b1.w;
  }
  bf16x8 v;
  v[0] = (short)f2bf(a.x * invl); v[1] = (short)f2bf(a.y * invl);
  v[2] = (short)f2bf(a.z * invl); v[3] = (short)f2bf(a.w * invl);
  v[4] = (short)f2bf(b.x * invl); v[5] = (short)f2bf(b.y * invl);
  v[6] = (short)f2bf(b.z * invl); v[7] = (short)f2bf(b.w * invl);
  *((bf16x8*)merged + i) = v;
  if ((c & 63) == 0) LI[h * 2048 + q] = invl;
}

// ---------- sweep 2: normalized colsums, KV-SPLIT (keys < 1920) ----------
// Block = 128 q x 1 head x <=8 key tiles; splits per qb: 1+qb/4 (40 blocks/head).
__global__ __launch_bounds__(256) void attn_colsum(
    const ushort_t* __restrict__ Qr, const ushort_t* __restrict__ Kr,
    const float* __restrict__ LI, float* __restrict__ ssum) {
  const int bx = blockIdx.x;
  const int h = blockIdx.y;
  int qb, si, nsp;
  if (bx < 16)      { nsp = 4; qb = 15 - (bx >> 2); si = bx & 3; }
  else if (bx < 28) { nsp = 3; const int r = bx - 16; qb = 11 - r / 3; si = r % 3; }
  else if (bx < 36) { nsp = 2; const int r = bx - 28; qb = 7 - (r >> 1); si = r & 1; }
  else              { nsp = 1; qb = 39 - bx; si = 0; }
  const int nt2 = min((qb + 1) * 2, 30);
  const int kt0 = (nt2 * si) / nsp, kt1 = (nt2 * (si + 1)) / nsp;
  const int q0 = qb * 128;
  const int tid = threadIdx.x, wave = tid >> 6, lane = tid & 63;
  const int quad = lane >> 4, col = lane & 15;
  const int qw = q0 + wave * 32;

  __shared__ __align__(16) ushort_t kbuf[64 * 72];
  __shared__ float cs[512];

  const int c0 = tid * 2;
  const int srow = c0 >> 3, sg = c0 & 7;

  bf16x8 qf[2][2];
#pragma unroll
  for (int i = 0; i < 2; ++i)
#pragma unroll
    for (int s = 0; s < 2; ++s)
      qf[i][s] = *(const bf16x8*)(Qr + (size_t)(qw + i * 16 + col) * 4544 + h * 64 + s * 32 + quad * 8);

  float linv2[2][4];
#pragma unroll
  for (int i = 0; i < 2; ++i)
#pragma unroll
    for (int r = 0; r < 4; ++r)
      linv2[i][r] = LI[h * 2048 + qw + i * 16 + quad * 4 + r];

  const int cov = (kt1 - kt0) * 64;
  for (int j = tid; j < cov; j += 256) cs[j] = 0.f;

  for (int t = kt0; t < kt1; ++t) {
    const int kbase = t * 64;
    __syncthreads();                                 // orders cs zeroing too (t==kt0)
    {
      const ushort_t* ks = Kr + (size_t)(kbase + srow) * 64 + sg * 8;
      ushort_t* kd = kbuf + srow * 72 + sg * 8;
      *(bf16x8*)kd = *(const bf16x8*)ks;
      *(bf16x8*)(kd + 8) = *(const bf16x8*)(ks + 8);
    }
    __syncthreads();
    if (kbase > qw + 31) continue;

    bf16x8 kf[4][2];
#pragma unroll
    for (int n = 0; n < 4; ++n) {
      kf[n][0] = *(const bf16x8*)(kbuf + (n * 16 + col) * 72 + quad * 8);
      kf[n][1] = *(const bf16x8*)(kbuf + (n * 16 + col) * 72 + 32 + quad * 8);
    }
    float accn[4] = {0.f, 0.f, 0.f, 0.f};
#pragma unroll
    for (int i = 0; i < 2; ++i) {
      const int qmin = qw + i * 16;
      const int qmax = qmin + 15;
      if (kbase > qmax) continue;
#pragma unroll
      for (int n = 0; n < 4; ++n) {
        const int kb2 = kbase + n * 16;
        if (kb2 > qmax) continue;
        f32x4 sacc = __builtin_amdgcn_mfma_f32_16x16x32_bf16(qf[i][0], kf[n][0],
                       (f32x4){0.f, 0.f, 0.f, 0.f}, 0, 0, 0);
        sacc = __builtin_amdgcn_mfma_f32_16x16x32_bf16(qf[i][1], kf[n][1], sacc, 0, 0, 0);
        if (kb2 + 15 <= qmin) {
#pragma unroll
          for (int r = 0; r < 4; ++r)
            accn[n] += __builtin_amdgcn_exp2f(sacc[r] - EXP_BIAS) * linv2[i][r];
        } else {
#pragma unroll
          for (int r = 0; r < 4; ++r) {
            const int q = qmin + quad * 4 + r;
            const int key = kb2 + col;
            const float px = __builtin_amdgcn_exp2f(sacc[r] - EXP_BIAS) * linv2[i][r];
            accn[n] += (key <= q) ? px : 0.f;
          }
        }
      }
    }
#pragma unroll
    for (int n = 0; n < 4; ++n) {
      float v = accn[n];
      v += __shfl_xor(v, 16, 64);
      v += __shfl_xor(v, 32, 64);
      if (quad == 0) atomicAdd(&cs[kbase - kt0 * 64 + n * 16 + col], v);
    }
  }

  __syncthreads();
  for (int j = tid; j < cov; j += 256) atomicAdd(&ssum[kt0 * 64 + j], cs[j]);
}

// ---------- fallback monolithic attn (r3, verified) ----------
__global__ __launch_bounds__(256) void attn_flash(
    const ushort_t* __restrict__ Qr, const ushort_t* __restrict__ Kr,
    const ushort_t* __restrict__ Vt, ushort_t* __restrict__ merged,
    float* __restrict__ ssum) {
  const int qb = (int)gridDim.x - 1 - (int)blockIdx.x;
  const int h = blockIdx.y;
  const int q0 = qb * 128;
  const int tid = threadIdx.x, wave = tid >> 6, lane = tid & 63;
  const int quad = lane >> 4, col = lane & 15;
  const int qw = q0 + wave * 32;
  const int ntiles = (qb + 1) * 2;

  __shared__ __align__(16) ushort_t kbuf[64 * 72];
  __shared__ __align__(16) ushort_t vbuf[64 * 72];
  __shared__ __align__(16) char pcs[4 * 32 * 72 * 2];
  ushort_t* pbuf = (ushort_t*)pcs + wave * (32 * 72);
  float* cs = (float*)pcs;

  const int c0 = tid * 2;
  const int srow = c0 >> 3, sg = c0 & 7;

  bf16x8 qf[2][2];
#pragma unroll
  for (int nt = 0; nt < 2; ++nt)
#pragma unroll
    for (int s = 0; s < 2; ++s)
      qf[nt][s] = *(const bf16x8*)(Qr + (size_t)(qw + nt * 16 + col) * 4544 + h * 64 + s * 32 + quad * 8);

  f32x4 oacc[2][4];
  float l[2] = {0.f, 0.f};
#pragma unroll
  for (int nt = 0; nt < 2; ++nt)
#pragma unroll
    for (int m = 0; m < 4; ++m) oacc[nt][m] = (f32x4){0.f, 0.f, 0.f, 0.f};

  for (int t = 0; t < ntiles; ++t) {
    const int kbase = t * 64;
    __syncthreads();
    {
      const ushort_t* ks = Kr + (size_t)(kbase + srow) * 64 + sg * 8;
      ushort_t* kd = kbuf + srow * 72 + sg * 8;
      *(bf16x8*)kd = *(const bf16x8*)ks;
      *(bf16x8*)(kd + 8) = *(const bf16x8*)(ks + 8);
      const ushort_t* vs = Vt + (size_t)srow * 2048 + kbase + sg * 8;
      ushort_t* vd = vbuf + srow * 72 + sg * 8;
      *(bf16x8*)vd = *(const bf16x8*)vs;
      *(bf16x8*)(vd + 8) = *(const bf16x8*)(vs + 8);
    }
    __syncthreads();
    if (kbase > qw + 31) continue;

    bf16x8 kf[4][2];
#pragma unroll
    for (int m = 0; m < 4; ++m) {
      kf[m][0] = *(const bf16x8*)(kbuf + (m * 16 + col) * 72 + quad * 8);
      kf[m][1] = *(const bf16x8*)(kbuf + (m * 16 + col) * 72 + 32 + quad * 8);
    }
#pragma unroll
    for (int nt = 0; nt < 2; ++nt) {
      const int qmin = qw + nt * 16;
      const int qtop = qmin + 15;
      if (kbase > qtop) continue;
      const int q = qmin + col;
#pragma unroll
      for (int m = 0; m < 4; ++m) {
        const int kb2 = kbase + m * 16;
        s16x4 pk;
        if (kb2 > qtop) {
          pk[0] = 0; pk[1] = 0; pk[2] = 0; pk[3] = 0;
          *(s16x4*)(pbuf + (nt * 16 + col) * 72 + m * 16 + quad * 4) = pk;
          continue;
        }
        f32x4 sacc = (f32x4){0.f, 0.f, 0.f, 0.f};
        sacc = __builtin_amdgcn_mfma_f32_16x16x32_bf16(kf[m][0], qf[nt][0], sacc, 0, 0, 0);
        sacc = __builtin_amdgcn_mfma_f32_16x16x32_bf16(kf[m][1], qf[nt][1], sacc, 0, 0, 0);
        float ls = 0.f;
        if (kb2 + 15 <= qmin) {
#pragma unroll
          for (int r = 0; r < 4; ++r) {
            const float px = __builtin_amdgcn_exp2f(sacc[r] - EXP_BIAS);
            ls += px;
            pk[r] = (short)f2bf(px);
          }
        } else {
#pragma unroll
          for (int r = 0; r < 4; ++r) {
            const int key = kb2 + quad * 4 + r;
            const float px = __builtin_amdgcn_exp2f(sacc[r] - EXP_BIAS);
            const float p = (key <= q) ? px : 0.f;
            ls += p;
            pk[r] = (short)f2bf(p);
          }
        }
        l[nt] += ls;
        *(s16x4*)(pbuf + (nt * 16 + col) * 72 + m * 16 + quad * 4) = pk;
      }
    }
#pragma unroll
    for (int ch = 0; ch < 2; ++ch) {
      if (kbase + ch * 32 > qw + 31) continue;
      bf16x8 vf[4];
#pragma unroll
      for (int m = 0; m < 4; ++m)
        vf[m] = *(const bf16x8*)(vbuf + (m * 16 + col) * 72 + ch * 32 + quad * 8);
#pragma unroll
      for (int nt = 0; nt < 2; ++nt) {
        if (kbase + ch * 32 > qw + nt * 16 + 15) continue;
        const bf16x8 pf = *(const bf16x8*)(pbuf + (nt * 16 + col) * 72 + ch * 32 + quad * 8);
#pragma unroll
        for (int m = 0; m < 4; ++m)
          oacc[nt][m] = __builtin_amdgcn_mfma_f32_16x16x32_bf16(vf[m], pf, oacc[nt][m], 0, 0, 0);
      }
    }
  }

  float invl[2];
#pragma unroll
  for (int nt = 0; nt < 2; ++nt) {
    float v = l[nt];
    v += __shfl_xor(v, 16, 64);
    v += __shfl_xor(v, 32, 64);
    invl[nt] = 1.0f / v;
  }

#pragma unroll
  for (int nt = 0; nt < 2; ++nt)
#pragma unroll
    for (int m = 0; m < 4; ++m) {
      s16x4 ok;
#pragma unroll
      for (int r = 0; r < 4; ++r) ok[r] = (short)f2bf(oacc[nt][m][r] * invl[nt]);
      *(s16x4*)(merged + (size_t)(qw + nt * 16 + col) * 4544 + h * 64 + m * 16 + quad * 4) = ok;
    }

  float linv2[2][4];
#pragma unroll
  for (int i = 0; i < 2; ++i)
#pragma unroll
    for (int r = 0; r < 4; ++r) linv2[i][r] = __shfl(invl[i], quad * 4 + r, 16);

  __syncthreads();
  const int nk2 = min(ntiles * 64, 1920);
  const int nt2 = min(ntiles, 30);
  for (int j = tid; j < nk2; j += 256) cs[j] = 0.f;

  for (int t = 0; t < nt2; ++t) {
    const int kbase = t * 64;
    __syncthreads();
    {
      const ushort_t* ks = Kr + (size_t)(kbase + srow) * 64 + sg * 8;
      ushort_t* kd = kbuf + srow * 72 + sg * 8;
      *(bf16x8*)kd = *(const bf16x8*)ks;
      *(bf16x8*)(kd + 8) = *(const bf16x8*)(ks + 8);
    }
    __syncthreads();
    if (kbase > qw + 31) continue;

    bf16x8 kf[4][2];
#pragma unroll
    for (int n = 0; n < 4; ++n) {
      kf[n][0] = *(const bf16x8*)(kbuf + (n * 16 + col) * 72 + quad * 8);
      kf[n][1] = *(const bf16x8*)(kbuf + (n * 16 + col) * 72 + 32 + quad * 8);
    }
    float accn[4] = {0.f, 0.f, 0.f, 0.f};
#pragma unroll
    for (int i = 0; i < 2; ++i) {
      const int qmin = qw + i * 16;
      const int qmax = qmin + 15;
      if (kbase > qmax) continue;
#pragma unroll
      for (int n = 0; n < 4; ++n) {
        const int kb2 = kbase + n * 16;
        if (kb2 > qmax) continue;
        f32x4 sacc = __builtin_amdgcn_mfma_f32_16x16x32_bf16(qf[i][0], kf[n][0],
                       (f32x4){0.f, 0.f, 0.f, 0.f}, 0, 0, 0);
        sacc = __builtin_amdgcn_mfma_f32_16x16x32_bf16(qf[i][1], kf[n][1], sacc, 0, 0, 0);
        if (kb2 + 15 <= qmin) {
#pragma unroll
          for (int r = 0; r < 4; ++r)
            accn[n] += __builtin_amdgcn_exp2f(sacc[r] - EXP_BIAS) * linv2[i][r];
        } else {
#pragma unroll
          for (int r = 0; r < 4; ++r) {
            const int q = qmin + quad * 4 + r;
            const int key = kb2 + col;
            const float px = __builtin_amdgcn_exp2f(sacc[r] - EXP_BIAS) * linv2[i][r];
            accn[n] += (key <= q) ? px : 0.f;
          }
        }
      }
    }
#pragma unroll
    for (int n = 0; n < 4; ++n) {
      float v = accn[n];
      v += __shfl_xor(v, 16, 64);
      v += __shfl_xor(v, 32, 64);
      if (quad == 0) atomicAdd(&cs[kbase + n * 16 + col], v);
    }
  }

  __syncthreads();
  for (int j = tid; j < nk2; j += 256) atomicAdd(&ssum[j], cs[j]);
}

// ---------- top-k(128) of ssum[0..1919] -> mask (2049 floats) ----------
// PARALLEL: 9 blocks x 256 threads, 1 output/thread; rank loop reads float4
// (4 independent LDS loads/iter, unrolled) so LDS latency overlaps instead of
// serializing (the old 1-block version was ~144us: 1 CU, dependent ds_read chain).
__global__ __launch_bounds__(256) void topk_mask(
    const float* __restrict__ ssum, float* __restrict__ maskout) {
  __shared__ __align__(16) float sv[1920];
  for (int i = threadIdx.x; i < 1920; i += 256) sv[i] = ssum[i];
  __syncthreads();
  const int i = blockIdx.x * 256 + threadIdx.x;
  if (i >= 2049) return;
  float o;
  if (i >= 1921) o = 1.f;
  else if (i == 1920) o = 0.f;
  else {
    const float v = sv[i];
    int rank = 0;
#pragma unroll 4
    for (int j = 0; j < 1920; j += 4) {
      const float4 w = *(const float4*)&sv[j];
      rank += (w.x > v) || (w.x == v && (j + 0) < i);
      rank += (w.y > v) || (w.y == v && (j + 1) < i);
      rank += (w.z > v) || (w.z == v && (j + 2) < i);
      rank += (w.w > v) || (w.w == v && (j + 3) < i);
    }
    o = (rank < 128) ? 1.f : 0.f;
  }
  maskout[i] = o;
}

// ---------- launch ----------
extern "C" void kernel_launch(void* const* d_in, const int* in_sizes, int n_in,
                              void* d_out, int out_size, void* d_ws, size_t ws_size,
                              hipStream_t stream) {
  (void)in_sizes; (void)n_in; (void)out_size;
  const float* hs      = (const float*)d_in[0];   // 1x2048x4544
  const float* w_qkv   = (const float*)d_in[1];   // 4544x4672
  const float* w_dense = (const float*)d_in[2];   // 4544x4544
  float* out = (float*)d_out;                     // 2048*4544 + 2049

  char* ws = (char*)d_ws;
  constexpr size_t OFF_WT    = 0;                        // 4736x4544 bf16
  constexpr size_t OFF_HSB   = 43040768;                 // 2048x4544 bf16 (reused as merged)
  constexpr size_t OFF_FUSED = OFF_HSB + 18612224;       // 2048x4672 fp32 (reused as Opart0)
  constexpr size_t OFF_QR    = OFF_FUSED + 38273024;     // 2048x4544 bf16
  constexpr size_t OFF_KR    = OFF_QR + 18612224;        // 2048x64 bf16
  constexpr size_t OFF_VT    = OFF_KR + 262144;          // 64x2048 bf16
  constexpr size_t OFF_SS    = OFF_VT + 262144;          // 2048 fp32
  constexpr size_t OFF_F2    = OFF_SS + 8192;            // 2048x4672 fp32 (split-K C1 / Opart1)
  constexpr size_t OFF_LP0   = OFF_F2 + 38273024;        // 71x2048 fp32
  constexpr size_t OFF_LP1   = OFF_LP0 + 581632;         // 71x2048 fp32
  constexpr size_t OFF_LI    = OFF_LP1 + 581632;         // 71x2048 fp32
  constexpr size_t WS_NEED   = OFF_LI + 581632;          // ~151.7 MiB

  ushort_t* wT     = (ushort_t*)(ws + OFF_WT);
  ushort_t* hsb    = (ushort_t*)(ws + OFF_HSB);
  float*    fused  = (float*)(ws + OFF_FUSED);
  ushort_t* qr     = (ushort_t*)(ws + OFF_QR);
  ushort_t* kr     = (ushort_t*)(ws + OFF_KR);
  ushort_t* vt     = (ushort_t*)(ws + OFF_VT);
  float*    ssum   = (float*)(ws + OFF_SS);
  float*    fused1 = (float*)(ws + OFF_F2);
  float*    lp0    = (float*)(ws + OFF_LP0);
  float*    lp1    = (float*)(ws + OFF_LP1);
  float*    li     = (float*)(ws + OFF_LI);

  const int split = (ws_size >= WS_NEED) ? 1 : 0;        // fall back if ws too small

  f32_to_bf16_vec<<<4544, 256, 0, stream>>>(hs, hsb, 2048 * 4544 / 8);
  transpose_w_bf16<<<dim3(148, 142), 256, 0, stream>>>(w_qkv, wT, 4672, 4544);
  if (split) {
    gemm_bt_128<<<dim3(32, 37), 256, 0, stream>>>(hsb, wT, fused, fused1, 4672, 4544, 4672, 1);
    rope_split<<<2048, 256, 0, stream>>>(fused, fused1, 1, qr, kr, vt, ssum);
  } else {
    gemm_bt_128<<<dim3(16, 37), 256, 0, stream>>>(hsb, wT, fused, fused, 4672, 4544, 4672, 0);
    rope_split<<<2048, 256, 0, stream>>>(fused, fused, 0, qr, kr, vt, ssum);
  }
  transpose_w_bf16<<<dim3(144, 142), 256, 0, stream>>>(w_dense, wT, 4544, 4544);
  if (split) {
    attn_sweep1<<<dim3(24, 71), 256, 0, stream>>>(qr, kr, vt, fused, fused1, lp0, lp1);
    attn_merge<<<4544, 256, 0, stream>>>(fused, fused1, lp0, lp1, hsb, li);
    attn_colsum<<<dim3(40, 71), 256, 0, stream>>>(qr, kr, li, ssum);
  } else {
    attn_flash<<<dim3(16, 71), 256, 0, stream>>>(qr, kr, vt, hsb, ssum);
  }
  topk_mask<<<9, 256, 0, stream>>>(ssum, out + (size_t)2048 * 4544);
  if (split) {
    gemm_bt_128<<<dim3(32, 36), 256, 0, stream>>>(hsb, wT, out, fused1, 4544, 4544, 4544, 1);
    add_inplace_f4<<<9088, 256, 0, stream>>>(out, fused1, 2048 * 4544 / 4);
  } else {
    gemm_bt_128<<<dim3(16, 36), 256, 0, stream>>>(hsb, wT, out, out, 4544, 4544, 4544, 0);
  }
}

// Round 7
// 705.612 us; speedup vs baseline: 1.4130x; 1.0165x over previous
//
#include <hip/hip_runtime.h>

typedef __attribute__((ext_vector_type(8))) short bf16x8;
typedef __attribute__((ext_vector_type(4))) short s16x4;
typedef __attribute__((ext_vector_type(4))) float f32x4;
typedef unsigned short ushort_t;

#define LOG2E 1.44269504088896340736f
#define EXP_BIAS 23.08312066f          /* 16 * LOG2E */
#define Q_SCALE 0.18033688f            /* 0.125 * LOG2E */

// ---------- helpers ----------
__device__ __forceinline__ unsigned short f2bf(float x) {
  unsigned int u = __float_as_uint(x);
  u = (u + 0x7FFFu + ((u >> 16) & 1u)) >> 16;   // RNE
  return (unsigned short)u;
}

__device__ __forceinline__ void async16(void* lds_dst, const void* gsrc) {
  __builtin_amdgcn_global_load_lds(
      (const __attribute__((address_space(1))) void*)gsrc,
      (__attribute__((address_space(3))) void*)lds_dst, 16, 0, 0);
}

// ---------- fp32 -> bf16 row-major (vectorized) ----------
__global__ __launch_bounds__(256) void f32_to_bf16_vec(
    const float* __restrict__ in, ushort_t* __restrict__ out, int n8) {
  int i = blockIdx.x * 256 + threadIdx.x;
  if (i >= n8) return;
  const float4* p = (const float4*)in + (size_t)i * 2;
  float4 a = p[0], b = p[1];
  bf16x8 v;
  v[0] = (short)f2bf(a.x); v[1] = (short)f2bf(a.y);
  v[2] = (short)f2bf(a.z); v[3] = (short)f2bf(a.w);
  v[4] = (short)f2bf(b.x); v[5] = (short)f2bf(b.y);
  v[6] = (short)f2bf(b.z); v[7] = (short)f2bf(b.w);
  *((bf16x8*)out + i) = v;
}

// ---------- transpose fp32 (Kd x N) -> bf16 (Npad x Kd), zero-pad rows >= N ----------
__global__ __launch_bounds__(256) void transpose_w_bf16(
    const float* __restrict__ in, ushort_t* __restrict__ out, int N, int Kd) {
  __shared__ float tile[32][33];
  const int tx = threadIdx.x & 31, ty = threadIdx.x >> 5;
  const int n0 = blockIdx.x * 32, k0 = blockIdx.y * 32;
#pragma unroll
  for (int yy = 0; yy < 32; yy += 8) {
    int k = k0 + ty + yy;
    int n = n0 + tx;
    tile[ty + yy][tx] = (n < N) ? in[(size_t)k * N + n] : 0.f;
  }
  __syncthreads();
#pragma unroll
  for (int yy = 0; yy < 32; yy += 8) {
    int n = n0 + ty + yy;
    int k = k0 + tx;
    out[(size_t)n * Kd + k] = f2bf(tile[tx][ty + yy]);
  }
}

// ---------- 128x128-tile bf16 GEMM, BK=64, C = A(MxK) @ Bt(NpadxK)^T, fp32 out ----------
// split==1: blockIdx.x&1 selects K-half (2304/2240, both %64==0) and output
// buffer (C0 or C1); halves summed by the CONSUMER (no atomics, no zeroing).
__global__ __launch_bounds__(256) void gemm_bt_128(
    const ushort_t* __restrict__ A, const ushort_t* __restrict__ Bt,
    float* __restrict__ C0, float* __restrict__ C1,
    int N, int K, int ldc, int split) {
  __shared__ __align__(16) char lds[32768];  // half0: A[0,8K) B[8K,16K); half1: +16K
  const int tid = threadIdx.x;
  const int lane = tid & 63, wave = tid >> 6;
  const int quad = lane >> 4, col = lane & 15;
  const int bm = split ? ((int)blockIdx.x >> 1) : (int)blockIdx.x;
  const int half = split ? ((int)blockIdx.x & 1) : 0;
  const int bn = blockIdx.y;
  float* __restrict__ C = half ? C1 : C0;
  int ks, ke;
  if (split) {
    const int s0 = ((((K >> 6) + 1) >> 1) << 6);         // 2304 for K=4544
    ks = half ? s0 : 0;
    ke = half ? K : s0;
  } else { ks = 0; ke = K; }
  const int wr = (wave >> 1) * 64, wc = (wave & 1) * 64;

  const int c0 = tid, c1 = tid + 256;
  const int r0 = c0 >> 2, r1 = c1 >> 2;
  const int l0 = (c0 & 3) ^ ((r0 >> 1) & 3);
  const int l1 = (c1 & 3) ^ ((r1 >> 1) & 3);
  const ushort_t* a0 = A + (size_t)(bm * 128 + r0) * K + l0 * 8;
  const ushort_t* a1 = A + (size_t)(bm * 128 + r1) * K + l1 * 8;
  const ushort_t* b0 = Bt + (size_t)(bn * 128 + r0) * K + l0 * 8;
  const ushort_t* b1 = Bt + (size_t)(bn * 128 + r1) * K + l1 * 8;
  const int wb = wave * 1024;

  f32x4 acc[4][4];
#pragma unroll
  for (int i = 0; i < 4; ++i)
#pragma unroll
    for (int j = 0; j < 4; ++j) acc[i][j] = (f32x4){0.f, 0.f, 0.f, 0.f};

  const int ccsw = (col >> 1) & 3;
  int aoff[4], boff[4];
#pragma unroll
  for (int t = 0; t < 4; ++t) {
    aoff[t] = (wr + t * 16 + col) * 64 + ((quad ^ ccsw) << 4);
    boff[t] = 8192 + (wc + t * 16 + col) * 64 + ((quad ^ ccsw) << 4);
  }

#pragma unroll 1
  for (int k = ks; k < ke; k += 64) {
    __syncthreads();
    async16(lds + wb,                   a0 + k);
    async16(lds + wb + 4096,            a1 + k);
    async16(lds + 8192 + wb,            b0 + k);
    async16(lds + 8192 + wb + 4096,     b1 + k);
    async16(lds + 16384 + wb,           a0 + k + 32);
    async16(lds + 16384 + wb + 4096,    a1 + k + 32);
    async16(lds + 24576 + wb,           b0 + k + 32);
    async16(lds + 24576 + wb + 4096,    b1 + k + 32);
    __syncthreads();
#pragma unroll
    for (int kk = 0; kk < 2; ++kk) {
      const char* base = lds + kk * 16384;
      bf16x8 af[4], bfr[4];
#pragma unroll
      for (int t = 0; t < 4; ++t) {
        af[t]  = *(const bf16x8*)(base + aoff[t]);
        bfr[t] = *(const bf16x8*)(base + boff[t]);
      }
#pragma unroll
      for (int i = 0; i < 4; ++i)
#pragma unroll
        for (int j = 0; j < 4; ++j)
          acc[i][j] = __builtin_amdgcn_mfma_f32_16x16x32_bf16(af[i], bfr[j], acc[i][j], 0, 0, 0);
    }
  }

#pragma unroll
  for (int i = 0; i < 4; ++i) {
    const int row = bm * 128 + wr + i * 16 + quad * 4;
#pragma unroll
    for (int j = 0; j < 4; ++j) {
      const int cc = bn * 128 + wc + j * 16 + col;
      if (cc < N) {
#pragma unroll
        for (int r = 0; r < 4; ++r)
          C[(size_t)(row + r) * ldc + cc] = acc[i][j][r];
      }
    }
  }
}

// ---------- out[i] += src[i], float4 ----------
__global__ __launch_bounds__(256) void add_inplace_f4(
    float* __restrict__ dst, const float* __restrict__ src, int n4) {
  int i = blockIdx.x * 256 + threadIdx.x;
  if (i >= n4) return;
  float4 a = ((const float4*)dst)[i];
  float4 b = ((const float4*)src)[i];
  a.x += b.x; a.y += b.y; a.z += b.z; a.w += b.w;
  ((float4*)dst)[i] = a;
}

// ---------- RoPE + split fused(2048x4672) -> Qr(/8*log2e, bf16), Kr, Vt; zero ssum ----------
__global__ __launch_bounds__(256) void rope_split(
    const float* __restrict__ f0, const float* __restrict__ f1, int two,
    ushort_t* __restrict__ Qr, ushort_t* __restrict__ Kr,
    ushort_t* __restrict__ Vt, float* __restrict__ ssum) {
  const int spos = blockIdx.x;
  const float* row0 = f0 + (size_t)spos * 4672;
  const float* row1 = f1 + (size_t)spos * 4672;
  if (blockIdx.x == 0)
    for (int j = threadIdx.x; j < 2048; j += 256) ssum[j] = 0.f;
  for (int c = threadIdx.x; c < 4672; c += 256) {
    const int hh = c >> 6, d = c & 63, j = d & 31;
    const float x = two ? (row0[c] + row1[c]) : row0[c];
    if (hh == 72) { Vt[(size_t)d * 2048 + spos] = f2bf(x); continue; }
    const float freq = __builtin_amdgcn_exp2f((float)j * -0.41524101186f);
    const float ang = (float)spos * freq;
    float sv, cv;
    __sincosf(ang, &sv, &cv);
    const int cp = (d < 32) ? c + 32 : c - 32;
    const float partner = two ? (row0[cp] + row1[cp]) : row0[cp];
    const float val = (d < 32) ? (x * cv - partner * sv) : (x * cv + partner * sv);
    if (hh == 71) Kr[(size_t)spos * 64 + d] = f2bf(val);
    else          Qr[(size_t)spos * 4544 + c] = f2bf(val * Q_SCALE);
  }
}

// ---------- attention sweep 1, KV-SPLIT partials, register-prefetch staging ----------
// Fixed-base softmax (p = exp2(s - bias), NO running max) => partial numerator
// O and denominator l over disjoint key ranges merge by pure addition.
// Block = 128 q x 1 head x key-tile range [kt0,kt1). qb>=8 split into two halves.
// T14 staging: per tile -> barrier(A: prior reads done); ds_write prefetched regs;
// ISSUE loads for t+1 (no wait); barrier(B: writes visible); compute(t). The
// global-load latency hides under compute(t)+barrier(A) instead of sitting
// exposed between the two barriers (the diagnosed ~3x latency serialization).
__global__ __launch_bounds__(256) void attn_sweep1(
    const ushort_t* __restrict__ Qr, const ushort_t* __restrict__ Kr,
    const ushort_t* __restrict__ Vt, float* __restrict__ Op0,
    float* __restrict__ Op1, float* __restrict__ lp0, float* __restrict__ lp1) {
  const int bx = blockIdx.x;
  const int h = blockIdx.y;
  int qb, kt0, kt1, buf1;
  if (bx < 8)       { qb = 15 - bx;       kt0 = 0;      kt1 = qb + 1;       buf1 = 0; }
  else if (bx < 16) { qb = 15 - (bx - 8); kt0 = qb + 1; kt1 = (qb + 1) * 2; buf1 = 1; }
  else              { qb = 23 - bx;       kt0 = 0;      kt1 = (qb + 1) * 2; buf1 = 0; }
  float* __restrict__ Op = buf1 ? Op1 : Op0;
  float* __restrict__ lp = buf1 ? lp1 : lp0;
  const int q0 = qb * 128;
  const int tid = threadIdx.x, wave = tid >> 6, lane = tid & 63;
  const int quad = lane >> 4, col = lane & 15;
  const int qw = q0 + wave * 32;

  __shared__ __align__(16) ushort_t kbuf[64 * 72];
  __shared__ __align__(16) ushort_t vbuf[64 * 72];
  __shared__ __align__(16) ushort_t pbuf_s[4 * 32 * 72];
  ushort_t* pbuf = pbuf_s + wave * (32 * 72);            // P^T: [32 q][64 k] stride 72

  const int c0 = tid * 2;
  const int srow = c0 >> 3, sg = c0 & 7;
  const ushort_t* kp = Kr + (size_t)srow * 64 + sg * 8;    // + t*4096
  const ushort_t* vp = Vt + (size_t)srow * 2048 + sg * 8;  // + t*64
  ushort_t* kd = kbuf + srow * 72 + sg * 8;
  ushort_t* vd = vbuf + srow * 72 + sg * 8;

  bf16x8 qf[2][2];
#pragma unroll
  for (int nt = 0; nt < 2; ++nt)
#pragma unroll
    for (int s = 0; s < 2; ++s)
      qf[nt][s] = *(const bf16x8*)(Qr + (size_t)(qw + nt * 16 + col) * 4544 + h * 64 + s * 32 + quad * 8);

  f32x4 oacc[2][4];
  float l[2] = {0.f, 0.f};
#pragma unroll
  for (int nt = 0; nt < 2; ++nt)
#pragma unroll
    for (int m = 0; m < 4; ++m) oacc[nt][m] = (f32x4){0.f, 0.f, 0.f, 0.f};

  // prologue: prefetch tile kt0 into registers
  bf16x8 rk0 = *(const bf16x8*)(kp + (size_t)kt0 * 4096);
  bf16x8 rk1 = *(const bf16x8*)(kp + (size_t)kt0 * 4096 + 8);
  bf16x8 rv0 = *(const bf16x8*)(vp + kt0 * 64);
  bf16x8 rv1 = *(const bf16x8*)(vp + kt0 * 64 + 8);

#pragma unroll 1
  for (int t = kt0; t < kt1; ++t) {
    const int kbase = t * 64;
    __syncthreads();                                     // (A) prior tile's reads done
    *(bf16x8*)kd = rk0;
    *(bf16x8*)(kd + 8) = rk1;
    *(bf16x8*)vd = rv0;
    *(bf16x8*)(vd + 8) = rv1;
    if (t + 1 < kt1) {                                   // issue next-tile loads, no wait
      rk0 = *(const bf16x8*)(kp + (size_t)(t + 1) * 4096);
      rk1 = *(const bf16x8*)(kp + (size_t)(t + 1) * 4096 + 8);
      rv0 = *(const bf16x8*)(vp + (t + 1) * 64);
      rv1 = *(const bf16x8*)(vp + (t + 1) * 64 + 8);
    }
    __syncthreads();                                     // (B) staging visible
    if (kbase > qw + 31) continue;                       // wave fully masked

    bf16x8 kf[4][2];                                     // A-frags: rows = keys
#pragma unroll
    for (int m = 0; m < 4; ++m) {
      kf[m][0] = *(const bf16x8*)(kbuf + (m * 16 + col) * 72 + quad * 8);
      kf[m][1] = *(const bf16x8*)(kbuf + (m * 16 + col) * 72 + 32 + quad * 8);
    }
#pragma unroll
    for (int nt = 0; nt < 2; ++nt) {
      const int qmin = qw + nt * 16;
      const int qtop = qmin + 15;
      if (kbase > qtop) continue;
      const int q = qmin + col;
#pragma unroll
      for (int m = 0; m < 4; ++m) {
        const int kb2 = kbase + m * 16;
        s16x4 pk;
        if (kb2 > qtop) {                                // fully above diagonal: p == 0
          pk[0] = 0; pk[1] = 0; pk[2] = 0; pk[3] = 0;
          *(s16x4*)(pbuf + (nt * 16 + col) * 72 + m * 16 + quad * 4) = pk;
          continue;
        }
        f32x4 sacc = (f32x4){0.f, 0.f, 0.f, 0.f};
        sacc = __builtin_amdgcn_mfma_f32_16x16x32_bf16(kf[m][0], qf[nt][0], sacc, 0, 0, 0);
        sacc = __builtin_amdgcn_mfma_f32_16x16x32_bf16(kf[m][1], qf[nt][1], sacc, 0, 0, 0);
        float ls = 0.f;
        if (kb2 + 15 <= qmin) {                          // fully below diagonal: no mask
#pragma unroll
          for (int r = 0; r < 4; ++r) {
            const float px = __builtin_amdgcn_exp2f(sacc[r] - EXP_BIAS);
            ls += px;
            pk[r] = (short)f2bf(px);
          }
        } else {                                         // diagonal block: per-element mask
#pragma unroll
          for (int r = 0; r < 4; ++r) {
            const int key = kb2 + quad * 4 + r;
            const float px = __builtin_amdgcn_exp2f(sacc[r] - EXP_BIAS);
            const float p = (key <= q) ? px : 0.f;
            ls += p;
            pk[r] = (short)f2bf(p);
          }
        }
        l[nt] += ls;
        *(s16x4*)(pbuf + (nt * 16 + col) * 72 + m * 16 + quad * 4) = pk;
      }
    }
    // PV: O^T += V^T · P^T
#pragma unroll
    for (int ch = 0; ch < 2; ++ch) {
      if (kbase + ch * 32 > qw + 31) continue;
      bf16x8 vf[4];
#pragma unroll
      for (int m = 0; m < 4; ++m)
        vf[m] = *(const bf16x8*)(vbuf + (m * 16 + col) * 72 + ch * 32 + quad * 8);
#pragma unroll
      for (int nt = 0; nt < 2; ++nt) {
        if (kbase + ch * 32 > qw + nt * 16 + 15) continue;
        const bf16x8 pf = *(const bf16x8*)(pbuf + (nt * 16 + col) * 72 + ch * 32 + quad * 8);
#pragma unroll
        for (int m = 0; m < 4; ++m)
          oacc[nt][m] = __builtin_amdgcn_mfma_f32_16x16x32_bf16(vf[m], pf, oacc[nt][m], 0, 0, 0);
      }
    }
  }

  // partial l: reduce across quads; lanes 0..15 hold cols 0..15
#pragma unroll
  for (int nt = 0; nt < 2; ++nt) {
    float v = l[nt];
    v += __shfl_xor(v, 16, 64);
    v += __shfl_xor(v, 32, 64);
    if (lane < 16) lp[h * 2048 + qw + nt * 16 + lane] = v;
  }

  // partial O^T numerator (fp32, un-normalized): float4 per (nt, m)
#pragma unroll
  for (int nt = 0; nt < 2; ++nt)
#pragma unroll
    for (int m = 0; m < 4; ++m)
      *(f32x4*)(Op + (size_t)(qw + nt * 16 + col) * 4544 + h * 64 + m * 16 + quad * 4) = oacc[nt][m];
}

// ---------- merge partials: O = (O0 [+O1]) / (l0 [+l1]) -> bf16; store invl ----------
__global__ __launch_bounds__(256) void attn_merge(
    const float* __restrict__ Op0, const float* __restrict__ Op1,
    const float* __restrict__ lp0, const float* __restrict__ lp1,
    ushort_t* __restrict__ merged, float* __restrict__ LI) {
  const int i = blockIdx.x * 256 + threadIdx.x;          // 8 floats per thread
  if (i >= 2048 * 4544 / 8) return;
  const int q = i / 568;                                 // 4544/8 = 568
  const int c = (i - q * 568) * 8;
  const int h = c >> 6;                                  // c..c+7 same head (c%8==0)
  const int dual = q >> 10;                              // q >= 1024 <=> qb >= 8
  float l = lp0[h * 2048 + q];
  if (dual) l += lp1[h * 2048 + q];
  const float invl = 1.0f / l;
  const float4* p0 = (const float4*)(Op0 + (size_t)q * 4544 + c);
  float4 a = p0[0], b = p0[1];
  if (dual) {
    const float4* p1 = (const float4*)(Op1 + (size_t)q * 4544 + c);
    float4 a1 = p1[0], b1 = p1[1];
    a.x += a1.x; a.y += a1.y; a.z += a1.z; a.w += a1.w;
    b.x += b1.x; b.y += b1.y; b.z += b1.z; b.w += b1.w;
  }
  bf16x8 v;
  v[0] = (short)f2bf(a.x * invl); v[1] = (short)f2bf(a.y * invl);
  v[2] = (short)f2bf(a.z * invl); v[3] = (short)f2bf(a.w * invl);
  v[4] = (short)f2bf(b.x * invl); v[5] = (short)f2bf(b.y * invl);
  v[6] = (short)f2bf(b.z * invl); v[7] = (short)f2bf(b.w * invl);
  *((bf16x8*)merged + i) = v;
  if ((c & 63) == 0) LI[h * 2048 + q] = invl;
}

// ---------- sweep 2: normalized colsums, KV-SPLIT (keys < 1920), reg-prefetch ----------
// Block = 128 q x 1 head x <=8 key tiles; splits per qb: 1+qb/4 (40 blocks/head).
__global__ __launch_bounds__(256) void attn_colsum(
    const ushort_t* __restrict__ Qr, const ushort_t* __restrict__ Kr,
    const float* __restrict__ LI, float* __restrict__ ssum) {
  const int bx = blockIdx.x;
  const int h = blockIdx.y;
  int qb, si, nsp;
  if (bx < 16)      { nsp = 4; qb = 15 - (bx >> 2); si = bx & 3; }
  else if (bx < 28) { nsp = 3; const int r = bx - 16; qb = 11 - r / 3; si = r % 3; }
  else if (bx < 36) { nsp = 2; const int r = bx - 28; qb = 7 - (r >> 1); si = r & 1; }
  else              { nsp = 1; qb = 39 - bx; si = 0; }
  const int nt2 = min((qb + 1) * 2, 30);
  const int kt0 = (nt2 * si) / nsp, kt1 = (nt2 * (si + 1)) / nsp;
  const int q0 = qb * 128;
  const int tid = threadIdx.x, wave = tid >> 6, lane = tid & 63;
  const int quad = lane >> 4, col = lane & 15;
  const int qw = q0 + wave * 32;

  __shared__ __align__(16) ushort_t kbuf[64 * 72];
  __shared__ float cs[512];

  const int c0 = tid * 2;
  const int srow = c0 >> 3, sg = c0 & 7;
  const ushort_t* kp = Kr + (size_t)srow * 64 + sg * 8;    // + t*4096
  ushort_t* kd = kbuf + srow * 72 + sg * 8;

  bf16x8 qf[2][2];
#pragma unroll
  for (int i = 0; i < 2; ++i)
#pragma unroll
    for (int s = 0; s < 2; ++s)
      qf[i][s] = *(const bf16x8*)(Qr + (size_t)(qw + i * 16 + col) * 4544 + h * 64 + s * 32 + quad * 8);

  float linv2[2][4];
#pragma unroll
  for (int i = 0; i < 2; ++i)
#pragma unroll
    for (int r = 0; r < 4; ++r)
      linv2[i][r] = LI[h * 2048 + qw + i * 16 + quad * 4 + r];

  const int cov = (kt1 - kt0) * 64;
  for (int j = tid; j < cov; j += 256) cs[j] = 0.f;

  // prologue: prefetch K tile kt0 into registers
  bf16x8 rk0 = *(const bf16x8*)(kp + (size_t)kt0 * 4096);
  bf16x8 rk1 = *(const bf16x8*)(kp + (size_t)kt0 * 4096 + 8);

#pragma unroll 1
  for (int t = kt0; t < kt1; ++t) {
    const int kbase = t * 64;
    __syncthreads();                                 // (A) prior reads done; cs zeroed
    *(bf16x8*)kd = rk0;
    *(bf16x8*)(kd + 8) = rk1;
    if (t + 1 < kt1) {                               // issue next-tile load, no wait
      rk0 = *(const bf16x8*)(kp + (size_t)(t + 1) * 4096);
      rk1 = *(const bf16x8*)(kp + (size_t)(t + 1) * 4096 + 8);
    }
    __syncthreads();                                 // (B) staging visible
    if (kbase > qw + 31) continue;

    bf16x8 kf[4][2];
#pragma unroll
    for (int n = 0; n < 4; ++n) {
      kf[n][0] = *(const bf16x8*)(kbuf + (n * 16 + col) * 72 + quad * 8);
      kf[n][1] = *(const bf16x8*)(kbuf + (n * 16 + col) * 72 + 32 + quad * 8);
    }
    float accn[4] = {0.f, 0.f, 0.f, 0.f};
#pragma unroll
    for (int i = 0; i < 2; ++i) {
      const int qmin = qw + i * 16;
      const int qmax = qmin + 15;
      if (kbase > qmax) continue;
#pragma unroll
      for (int n = 0; n < 4; ++n) {
        const int kb2 = kbase + n * 16;
        if (kb2 > qmax) continue;
        f32x4 sacc = __builtin_amdgcn_mfma_f32_16x16x32_bf16(qf[i][0], kf[n][0],
                       (f32x4){0.f, 0.f, 0.f, 0.f}, 0, 0, 0);
        sacc = __builtin_amdgcn_mfma_f32_16x16x32_bf16(qf[i][1], kf[n][1], sacc, 0, 0, 0);
        if (kb2 + 15 <= qmin) {
#pragma unroll
          for (int r = 0; r < 4; ++r)
            accn[n] += __builtin_amdgcn_exp2f(sacc[r] - EXP_BIAS) * linv2[i][r];
        } else {
#pragma unroll
          for (int r = 0; r < 4; ++r) {
            const int q = qmin + quad * 4 + r;
            const int key = kb2 + col;
            const float px = __builtin_amdgcn_exp2f(sacc[r] - EXP_BIAS) * linv2[i][r];
            accn[n] += (key <= q) ? px : 0.f;
          }
        }
      }
    }
#pragma unroll
    for (int n = 0; n < 4; ++n) {
      float v = accn[n];
      v += __shfl_xor(v, 16, 64);
      v += __shfl_xor(v, 32, 64);
      if (quad == 0) atomicAdd(&cs[kbase - kt0 * 64 + n * 16 + col], v);
    }
  }

  __syncthreads();
  for (int j = tid; j < cov; j += 256) atomicAdd(&ssum[kt0 * 64 + j], cs[j]);
}

// ---------- top-k(128) of ssum[0..1919] -> mask (2049 floats) ----------
// PARALLEL: 9 blocks x 256 threads, 1 output/thread; rank loop reads float4.
__global__ __launch_bounds__(256) void topk_mask(
    const float* __restrict__ ssum, float* __restrict__ maskout) {
  __shared__ __align__(16) float sv[1920];
  for (int i = threadIdx.x; i < 1920; i += 256) sv[i] = ssum[i];
  __syncthreads();
  const int i = blockIdx.x * 256 + threadIdx.x;
  if (i >= 2049) return;
  float o;
  if (i >= 1921) o = 1.f;
  else if (i == 1920) o = 0.f;
  else {
    const float v = sv[i];
    int rank = 0;
#pragma unroll 4
    for (int j = 0; j < 1920; j += 4) {
      const float4 w = *(const float4*)&sv[j];
      rank += (w.x > v) || (w.x == v && (j + 0) < i);
      rank += (w.y > v) || (w.y == v && (j + 1) < i);
      rank += (w.z > v) || (w.z == v && (j + 2) < i);
      rank += (w.w > v) || (w.w == v && (j + 3) < i);
    }
    o = (rank < 128) ? 1.f : 0.f;
  }
  maskout[i] = o;
}

// ---------- launch ----------
extern "C" void kernel_launch(void* const* d_in, const int* in_sizes, int n_in,
                              void* d_out, int out_size, void* d_ws, size_t ws_size,
                              hipStream_t stream) {
  (void)in_sizes; (void)n_in; (void)out_size;
  const float* hs      = (const float*)d_in[0];   // 1x2048x4544
  const float* w_qkv   = (const float*)d_in[1];   // 4544x4672
  const float* w_dense = (const float*)d_in[2];   // 4544x4544
  float* out = (float*)d_out;                     // 2048*4544 + 2049

  char* ws = (char*)d_ws;
  constexpr size_t OFF_WT    = 0;                        // 4736x4544 bf16
  constexpr size_t OFF_HSB   = 43040768;                 // 2048x4544 bf16 (reused as merged)
  constexpr size_t OFF_FUSED = OFF_HSB + 18612224;       // 2048x4672 fp32 (reused as Opart0)
  constexpr size_t OFF_QR    = OFF_FUSED + 38273024;     // 2048x4544 bf16
  constexpr size_t OFF_KR    = OFF_QR + 18612224;        // 2048x64 bf16
  constexpr size_t OFF_VT    = OFF_KR + 262144;          // 64x2048 bf16
  constexpr size_t OFF_SS    = OFF_VT + 262144;          // 2048 fp32
  constexpr size_t OFF_F2    = OFF_SS + 8192;            // 2048x4672 fp32 (split-K C1 / Opart1)
  constexpr size_t OFF_LP0   = OFF_F2 + 38273024;        // 71x2048 fp32
  constexpr size_t OFF_LP1   = OFF_LP0 + 581632;         // 71x2048 fp32
  constexpr size_t OFF_LI    = OFF_LP1 + 581632;         // 71x2048 fp32
  constexpr size_t WS_NEED   = OFF_LI + 581632;          // ~151.7 MiB

  ushort_t* wT     = (ushort_t*)(ws + OFF_WT);
  ushort_t* hsb    = (ushort_t*)(ws + OFF_HSB);
  float*    fused  = (float*)(ws + OFF_FUSED);
  ushort_t* qr     = (ushort_t*)(ws + OFF_QR);
  ushort_t* kr     = (ushort_t*)(ws + OFF_KR);
  ushort_t* vt     = (ushort_t*)(ws + OFF_VT);
  float*    ssum   = (float*)(ws + OFF_SS);
  float*    fused1 = (float*)(ws + OFF_F2);
  float*    lp0    = (float*)(ws + OFF_LP0);
  float*    lp1    = (float*)(ws + OFF_LP1);
  float*    li     = (float*)(ws + OFF_LI);

  const int split = (ws_size >= WS_NEED) ? 1 : 0;        // fall back if ws too small

  f32_to_bf16_vec<<<4544, 256, 0, stream>>>(hs, hsb, 2048 * 4544 / 8);
  transpose_w_bf16<<<dim3(148, 142), 256, 0, stream>>>(w_qkv, wT, 4672, 4544);
  if (split) {
    gemm_bt_128<<<dim3(32, 37), 256, 0, stream>>>(hsb, wT, fused, fused1, 4672, 4544, 4672, 1);
    rope_split<<<2048, 256, 0, stream>>>(fused, fused1, 1, qr, kr, vt, ssum);
  } else {
    gemm_bt_128<<<dim3(16, 37), 256, 0, stream>>>(hsb, wT, fused, fused, 4672, 4544, 4672, 0);
    rope_split<<<2048, 256, 0, stream>>>(fused, fused, 0, qr, kr, vt, ssum);
  }
  transpose_w_bf16<<<dim3(144, 142), 256, 0, stream>>>(w_dense, wT, 4544, 4544);
  attn_sweep1<<<dim3(24, 71), 256, 0, stream>>>(qr, kr, vt, fused, fused1, lp0, lp1);
  attn_merge<<<4544, 256, 0, stream>>>(fused, fused1, lp0, lp1, hsb, li);
  attn_colsum<<<dim3(40, 71), 256, 0, stream>>>(qr, kr, li, ssum);
  topk_mask<<<9, 256, 0, stream>>>(ssum, out + (size_t)2048 * 4544);
  if (split) {
    gemm_bt_128<<<dim3(32, 36), 256, 0, stream>>>(hsb, wT, out, fused1, 4544, 4544, 4544, 1);
    add_inplace_f4<<<9088, 256, 0, stream>>>(out, fused1, 2048 * 4544 / 4);
  } else {
    gemm_bt_128<<<dim3(16, 36), 256, 0, stream>>>(hsb, wT, out, out, 4544, 4544, 4544, 0);
  }
}